// Round 8
// baseline (503.438 us; speedup 1.0000x reference)
//
#include <hip/hip_runtime.h>

// MoE-LoRA linear, MI355X (gfx950).
// out = x @ base_w^T + 2.0 * ((x @ lora_A^T) * topk_gate_w) @ lora_B^T
// A_cat[8192][4608] = [ bf16(x) | bf16(SCALING * w_e * (x . lora_A_row)) ]
// W_cat[4096][4608] = [ bf16(base_w) | bf16(lora_B) ]
// out = A_cat @ W_cat^T via 256x256-tile 8-wave 4-phase counted-vmcnt GEMM,
// 16x16x32 bf16 MFMA, XOR-swizzled LDS, one-phase-ahead fragment reads,
// K-loop unrolled x2 so all LDS buffer bases are compile-time constants.
// Gating: single-pass fp32 logits + top-2 fused with x->bf16 (R6-proven;
// R7's K-split partials measured +17us WORSE -- reverted).

#define D_IN   4096
#define D_OUT  4096
#define NTOK   8192      // B*S
#define NE     32
#define RMOE   512       // E*R
#define KCAT   4608      // D_IN + RMOE
#define SCALING 2.0f

typedef unsigned short u16;
typedef __attribute__((ext_vector_type(4)))  float  f32x4;
typedef __attribute__((ext_vector_type(4)))  unsigned short u16x4;
typedef __attribute__((ext_vector_type(8)))  short  bf16x8;

__device__ __forceinline__ u16 f2bf(float f) {
  unsigned u = __float_as_uint(f);
  u += 0x7FFFu + ((u >> 16) & 1u);        // round-to-nearest-even
  return (u16)(u >> 16);
}

__device__ __forceinline__ void gload16(const void* g, void* l) {
  __builtin_amdgcn_global_load_lds(
      (const __attribute__((address_space(1))) unsigned*)g,
      (__attribute__((address_space(3))) unsigned*)l, 16, 0, 0);
}

#define BAR() do { asm volatile("" ::: "memory"); \
                   __builtin_amdgcn_s_barrier();  \
                   asm volatile("" ::: "memory"); } while (0)
#define WAITV6() asm volatile("s_waitcnt vmcnt(6)" ::: "memory")
#define WAITV4() asm volatile("s_waitcnt vmcnt(4)" ::: "memory")
#define WAITV0() asm volatile("s_waitcnt vmcnt(0)" ::: "memory")

// ---------------------------------------------------------------------------
// Kernel 1: fused prep.
//  blocks [0,256):    gating logits GEMM + top-2 + renorm -> wdense,
//                     fused with x -> bf16 into A_cat[:, 0:4096]
//  blocks [256,4864): weight conversion (wb = [base_w|lora_B], la = lora_A)
// ---------------------------------------------------------------------------
#define TT 32
#define KC 256

__global__ __launch_bounds__(256) void k_prep(
    const float* __restrict__ x, const float* __restrict__ gate_w,
    const float* __restrict__ base_w, const float* __restrict__ lora_B,
    const float* __restrict__ lora_A,
    float* __restrict__ wdense, u16* __restrict__ xb,
    u16* __restrict__ wb, u16* __restrict__ la)
{
  __shared__ float smem[2 * TT * KC];       // xs | gs  (64 KiB)
  __shared__ float lgt[TT * 36];
  __shared__ int   e1s[TT]; __shared__ int   e2s[TT];
  __shared__ float w1s[TT]; __shared__ float w2s[TT];
  const int tid = threadIdx.x;

  if (blockIdx.x >= 256) {                  // ---- weight-conversion path ----
    const int bid = blockIdx.x - 256;
    if (bid < D_OUT) {
      const float* src = base_w + (size_t)bid * D_IN;
      u16* dst = wb + (size_t)bid * KCAT;
#pragma unroll
      for (int i = 0; i < 4; ++i) {
        int c = tid + i * 256;
        f32x4 v = ((const f32x4*)src)[c];
        u16x4 h; h[0] = f2bf(v[0]); h[1] = f2bf(v[1]); h[2] = f2bf(v[2]); h[3] = f2bf(v[3]);
        ((u16x4*)dst)[c] = h;
      }
      if (tid < 128) {                      // lora_B row: 512 = 128 x float4
        f32x4 v = ((const f32x4*)(lora_B + (size_t)bid * RMOE))[tid];
        u16x4 h; h[0] = f2bf(v[0]); h[1] = f2bf(v[1]); h[2] = f2bf(v[2]); h[3] = f2bf(v[3]);
        ((u16x4*)(dst + D_IN))[tid] = h;
      }
    } else {
      int r = bid - D_OUT;                  // lora_A row 0..511
      const float* src = lora_A + (size_t)r * D_IN;
      u16* dst = la + (size_t)r * D_IN;
#pragma unroll
      for (int i = 0; i < 4; ++i) {
        int c = tid + i * 256;
        f32x4 v = ((const f32x4*)src)[c];
        u16x4 h; h[0] = f2bf(v[0]); h[1] = f2bf(v[1]); h[2] = f2bf(v[2]); h[3] = f2bf(v[3]);
        ((u16x4*)dst)[c] = h;
      }
    }
    return;
  }

  // ---- gating path ----
  float* xs = smem;
  float* gs = smem + TT * KC;
  const int lane = tid & 63, wave = tid >> 6;
  const int ks = lane >> 4, tg = (lane >> 2) & 3, eg = lane & 3;
  const int row0 = blockIdx.x * TT;
  const int kc0 = wave * 16 + ks * 4;

  float acc[8][8];
#pragma unroll
  for (int t = 0; t < 8; ++t)
#pragma unroll
    for (int e = 0; e < 8; ++e) acc[t][e] = 0.f;

  for (int kt = 0; kt < D_IN / KC; ++kt) {
    __syncthreads();
#pragma unroll
    for (int i = 0; i < 8; ++i) {           // stage x tile + emit bf16 copy
      int c = tid + i * 256;
      int tok = c >> 6, kq = c & 63;
      f32x4 v = ((const f32x4*)(x + (size_t)(row0 + tok) * D_IN + kt * KC))[kq];
      *(f32x4*)&xs[tok * KC + ((kq ^ (tok >> 3)) << 2)] = v;
      u16x4 h;
      h[0] = f2bf(v[0]); h[1] = f2bf(v[1]); h[2] = f2bf(v[2]); h[3] = f2bf(v[3]);
      ((u16x4*)(xb + (size_t)(row0 + tok) * KCAT + kt * KC))[kq] = h;
    }
#pragma unroll
    for (int i = 0; i < 8; ++i) {           // stage gate tile
      int c = tid + i * 256;
      int e = c >> 6, kq = c & 63;
      f32x4 v = ((const f32x4*)(gate_w + (size_t)e * D_IN + kt * KC))[kq];
      *(f32x4*)&gs[e * KC + ((kq ^ (e >> 3)) << 2)] = v;
    }
    __syncthreads();
#pragma unroll
    for (int j = 0; j < 4; ++j) {
      const int Kc = kc0 + j;
      f32x4 xv[8], gv[8];
#pragma unroll
      for (int t = 0; t < 8; ++t)
        xv[t] = *(const f32x4*)&xs[(tg * 8 + t) * KC + ((Kc ^ tg) << 2)];
#pragma unroll
      for (int e = 0; e < 8; ++e)
        gv[e] = *(const f32x4*)&gs[(eg * 8 + e) * KC + ((Kc ^ eg) << 2)];
#pragma unroll
      for (int t = 0; t < 8; ++t)
#pragma unroll
        for (int e = 0; e < 8; ++e)
#pragma unroll
          for (int m = 0; m < 4; ++m)
            acc[t][e] += xv[t][m] * gv[e][m];
    }
  }

#pragma unroll
  for (int t = 0; t < 8; ++t)
#pragma unroll
    for (int e = 0; e < 8; ++e) {
      float v = acc[t][e];
      v += __shfl_xor(v, 16);
      v += __shfl_xor(v, 32);
      acc[t][e] = v;
    }
  __syncthreads();
  float* red = smem;
  if (ks == 0) {
#pragma unroll
    for (int t = 0; t < 8; ++t)
#pragma unroll
      for (int e4 = 0; e4 < 8; e4 += 4) {
        f32x4 v = { acc[t][e4], acc[t][e4 + 1], acc[t][e4 + 2], acc[t][e4 + 3] };
        *(f32x4*)&red[(wave * 16 + tg * 4 + eg) * 64 + t * 8 + e4] = v;
      }
  }
  __syncthreads();
  {
    int tok = tid >> 3, e4 = (tid & 7) << 2;
    f32x4 s = {0.f, 0.f, 0.f, 0.f};
#pragma unroll
    for (int w = 0; w < 4; ++w)
      s += *(const f32x4*)&red[(w * 16 + (tok >> 3) * 4 + (e4 >> 3)) * 64 + (tok & 7) * 8 + (e4 & 7)];
    *(f32x4*)&lgt[tok * 36 + e4] = s;
  }
  __syncthreads();
  if (tid < TT) {
    float l1 = -1e30f; int e1 = 0;
    for (int e = 0; e < NE; ++e) { float v = lgt[tid * 36 + e]; if (v > l1) { l1 = v; e1 = e; } }
    float l2 = -1e30f; int e2 = 0;
    for (int e = 0; e < NE; ++e) { if (e == e1) continue; float v = lgt[tid * 36 + e]; if (v > l2) { l2 = v; e2 = e; } }
    float t = __expf(l2 - l1);
    float w2 = t / (1.f + t);
    e1s[tid] = e1; e2s[tid] = e2; w1s[tid] = 1.f - w2; w2s[tid] = w2;
  }
  __syncthreads();
#pragma unroll
  for (int i = 0; i < 4; ++i) {
    int c = tid + i * 256;
    int tok = c >> 5, e = c & 31;
    float v = (e == e1s[tok]) ? w1s[tok] : (e == e2s[tok]) ? w2s[tok] : 0.f;
    wdense[(size_t)(row0 + tok) * NE + e] = v;
  }
}

// ---------------------------------------------------------------------------
// Kernel 2: ax GEMM  (A_cat[:, :4096] @ lora_A^T) * w * SCALING -> A_cat tail
// 64x128 tile, 512 blocks (2 resident blocks/CU), BK=64, 4 waves (1Mx4N),
// 3-buffer pipeline 2 ahead, vmcnt(6), XOR swizzle.
// ---------------------------------------------------------------------------
__global__ __launch_bounds__(256) void k_gemm_ax(
    const u16* __restrict__ A, const u16* __restrict__ La,
    const float* __restrict__ wdense, u16* __restrict__ xb)
{
  __shared__ u16 sh[36864];                 // 3 bufs x (As 4096 | Bs 8192)
  const int nwg = gridDim.x;                // 512 (div by 8 -> bijective)
  int bid = blockIdx.x;
  int wg = (bid & 7) * (nwg >> 3) + (bid >> 3);
  const int tm = wg >> 2, tn = wg & 3;      // 128 m-tiles, 4 n-tiles
  const int tid = threadIdx.x;
  const int lane = tid & 63, wn = tid >> 6; // 4 waves split N
  const int l15 = lane & 15, g = lane >> 4;
  const int row0 = tm * 64, col0 = tn * 128;

  size_t offA[2], offB[4]; int dA[2], dB[4];
#pragma unroll
  for (int i = 0; i < 2; ++i) {
    int c = tid + i * 256;
    int r = c >> 3, s = (c & 7) ^ (r & 7);
    offA[i] = (size_t)(row0 + r) * KCAT + s * 8;
    dA[i] = c * 8;
  }
#pragma unroll
  for (int i = 0; i < 4; ++i) {
    int c = tid + i * 256;
    int r = c >> 3, s = (c & 7) ^ (r & 7);
    offB[i] = (size_t)(col0 + r) * D_IN + s * 8;
    dB[i] = c * 8;
  }

#define STGAX(b, kt) do { \
    _Pragma("unroll") for (int i = 0; i < 2; ++i) \
      gload16(A  + offA[i] + (size_t)(kt) * 64, &sh[(b) * 12288 + dA[i]]); \
    _Pragma("unroll") for (int i = 0; i < 4; ++i) \
      gload16(La + offB[i] + (size_t)(kt) * 64, &sh[(b) * 12288 + 4096 + dB[i]]); } while (0)

  f32x4 acc[4][2];
#pragma unroll
  for (int i = 0; i < 4; ++i)
#pragma unroll
    for (int j = 0; j < 2; ++j) acc[i][j] = (f32x4){0.f, 0.f, 0.f, 0.f};

  STGAX(0, 0);
  STGAX(1, 1);
  WAITV6();                                 // tile0 landed
  BAR();

  const int swz = (g ^ (l15 & 7)) * 8;
  for (int kt = 0; kt < D_IN / 64; ++kt) {  // 64 tiles
    if (kt + 2 < D_IN / 64) STGAX((kt + 2) % 3, kt + 2);
    const u16* As_ = &sh[(kt % 3) * 12288];
    const u16* Bs_ = &sh[(kt % 3) * 12288 + 4096];
    bf16x8 af[4][2], bfr[2][2];
#pragma unroll
    for (int i = 0; i < 4; ++i) {
      int ixa = (i * 16 + l15) * 64 + swz;
      af[i][0] = *(const bf16x8*)&As_[ixa]; af[i][1] = *(const bf16x8*)&As_[ixa ^ 32];
    }
#pragma unroll
    for (int j = 0; j < 2; ++j) {
      int ixb = (wn * 32 + j * 16 + l15) * 64 + swz;
      bfr[j][0] = *(const bf16x8*)&Bs_[ixb]; bfr[j][1] = *(const bf16x8*)&Bs_[ixb ^ 32];
    }
    __builtin_amdgcn_s_setprio(1);
#pragma unroll
    for (int i = 0; i < 4; ++i)
#pragma unroll
      for (int j = 0; j < 2; ++j)
#pragma unroll
        for (int kk = 0; kk < 2; ++kk)
          acc[i][j] = __builtin_amdgcn_mfma_f32_16x16x32_bf16(af[i][kk], bfr[j][kk], acc[i][j], 0, 0, 0);
    __builtin_amdgcn_s_setprio(0);
    if (kt >= D_IN / 64 - 2) WAITV0(); else WAITV6();
    BAR();
  }
#undef STGAX

  // epilogue: scale by gate weight, SCALING, store bf16 to A_cat tail
#pragma unroll
  for (int i = 0; i < 4; ++i) {
    int rbase = row0 + i * 16 + (g << 2);
#pragma unroll
    for (int j = 0; j < 2; ++j) {
      int cb = col0 + wn * 32 + j * 16 + l15;
#pragma unroll
      for (int q = 0; q < 4; ++q) {
        int trow = rbase + q;
        float wgt = wdense[(size_t)trow * NE + (cb >> 4)];
        xb[(size_t)trow * KCAT + D_IN + cb] = f2bf(acc[i][j][q] * wgt * SCALING);
      }
    }
  }
}

// ---------------------------------------------------------------------------
// Kernel 3: main GEMM  out = A_cat @ W_cat^T  (M=8192, N=4096, K=4608)
// 256x256 tile, 8 waves (2Mx4N), 16x16x32 bf16 MFMA, BK=64, double-buffered
// 128 KiB LDS, 4 phases/K-tile, counted vmcnt(4) x2 per tile, XOR-swizzled
// LDS, one-phase-ahead fragment reads. K-loop unrolled x2: all LDS buffer
// bases compile-time constants (ds_read imm-offset folding, less VALU).
// ---------------------------------------------------------------------------
#define NT (KCAT / 64)    // 72 (even)

__global__ __launch_bounds__(512, 2) void k_gemm_main(
    const u16* __restrict__ A, const u16* __restrict__ Bw, float* __restrict__ C)
{
  // [buf:2][op A|B:2][half:2][128 rows][64 cols] u16 = 128 KiB
  __shared__ u16 sh[65536];

  const int tid  = threadIdx.x;
  const int lane = tid & 63;
  const int wv   = tid >> 6;            // 0..7
  const int wm   = wv >> 2;             // 0..1
  const int wn   = wv & 3;              // 0..3
  const int l15  = lane & 15, g = lane >> 4;

  // T1: bijective XCD swizzle (512 blocks, 512 % 8 == 0)
  const int nwg = gridDim.x;
  int bid = blockIdx.x;
  int wg = (bid & 7) * (nwg >> 3) + (bid >> 3);
  const int tn = wg & 15, tm = wg >> 4; // 16 n-tiles, 32 m-tiles

  // LDS read addressing (T2 swizzle: slot ^= row&7; row&7 == l15&7)
  const int rsw   = (g ^ (l15 & 7)) * 8;
  const int aBase = (wm << 13) + l15 * 64 + rsw;
  const int bBase = 16384 + ((wn >> 1) << 13) + ((wn & 1) * 64 + l15) * 64 + rsw;

  // staging: pre-swizzled global sources, linear gload_lds dests
  const int c0 = tid, c1 = tid + 512;
  const int r0s = c0 >> 3, s0s = (c0 & 7) ^ (r0s & 7);
  const int r1s = c1 >> 3, s1s = (c1 & 7) ^ (r1s & 7);
  const size_t offc0 = (size_t)r0s * KCAT + s0s * 8;
  const size_t offc1 = (size_t)r1s * KCAT + s1s * 8;
  const u16* pA0a = A  + (size_t)(tm * 256 +   0) * KCAT + offc0;
  const u16* pA0b = A  + (size_t)(tm * 256 +   0) * KCAT + offc1;
  const u16* pA1a = A  + (size_t)(tm * 256 + 128) * KCAT + offc0;
  const u16* pA1b = A  + (size_t)(tm * 256 + 128) * KCAT + offc1;
  const u16* pB0a = Bw + (size_t)(tn * 256 +   0) * KCAT + offc0;
  const u16* pB0b = Bw + (size_t)(tn * 256 +   0) * KCAT + offc1;
  const u16* pB1a = Bw + (size_t)(tn * 256 + 128) * KCAT + offc0;
  const u16* pB1b = Bw + (size_t)(tn * 256 + 128) * KCAT + offc1;
  const int d0 = c0 * 8, d1 = c1 * 8;

#define STG(pa, pb, base) do { \
    gload16((pa), &sh[(base) + d0]); \
    gload16((pb), &sh[(base) + d1]); \
    (pa) += 64; (pb) += 64; } while (0)

#define MM4x2(MO, NO, AF, BF) do { \
    _Pragma("unroll") for (int m_ = 0; m_ < 4; ++m_) \
    _Pragma("unroll") for (int n_ = 0; n_ < 2; ++n_) \
    _Pragma("unroll") for (int kk_ = 0; kk_ < 2; ++kk_) \
      acc[m_ + (MO)][n_ + (NO)] = __builtin_amdgcn_mfma_f32_16x16x32_bf16( \
          AF[m_][kk_], BF[n_][kk_], acc[m_ + (MO)][n_ + (NO)], 0, 0, 0); } while (0)

// one K-tile with compile-time buffer base CB (0 or 32768).
// C12: stage next-tile A1/B1 into CB^32768; C34: stage tile+2 A0/B0 into CB;
// CRF: refill aA/bR from CB^32768 for the next tile.
#define TILE(CB, C12, C34, CRF) do { \
    /* P1: stage A1(next); read aB; MFMA Q00 = aA x bA */ \
    if (C12) STG(pA1a, pA1b, ((CB) ^ 32768) + 8192); \
    _Pragma("unroll") for (int m_ = 0; m_ < 4; ++m_) { \
      int ix = (CB) + aBase + (m_ + 4) * 1024; \
      aB[m_][0] = *(const bf16x8*)&sh[ix]; aB[m_][1] = *(const bf16x8*)&sh[ix ^ 32]; } \
    BAR(); \
    __builtin_amdgcn_s_setprio(1); MM4x2(0, 0, aA, bR); __builtin_amdgcn_s_setprio(0); \
    BAR(); \
    /* P2: stage B1(next); MFMA Q10 = aB x bA; refill bR <- bB; counted wait */ \
    if (C12) STG(pB1a, pB1b, ((CB) ^ 32768) + 24576); \
    BAR(); \
    __builtin_amdgcn_s_setprio(1); MM4x2(4, 0, aB, bR); __builtin_amdgcn_s_setprio(0); \
    _Pragma("unroll") for (int n_ = 0; n_ < 2; ++n_) { \
      int ix = (CB) + bBase + (n_ + 2) * 1024; \
      bR[n_][0] = *(const bf16x8*)&sh[ix]; bR[n_][1] = *(const bf16x8*)&sh[ix ^ 32]; } \
    WAITV4(); \
    BAR(); \
    /* P3: stage A0(tile+2); MFMA Q01 = aA x bB; refill aA <- next-tile A0 */ \
    if (C34) STG(pA0a, pA0b, (CB) + 0); \
    BAR(); \
    __builtin_amdgcn_s_setprio(1); MM4x2(0, 2, aA, bR); __builtin_amdgcn_s_setprio(0); \
    if (CRF) { _Pragma("unroll") for (int m_ = 0; m_ < 4; ++m_) { \
      int ix = ((CB) ^ 32768) + aBase + m_ * 1024; \
      aA[m_][0] = *(const bf16x8*)&sh[ix]; aA[m_][1] = *(const bf16x8*)&sh[ix ^ 32]; } } \
    BAR(); \
    /* P4: stage B0(tile+2); counted wait; MFMA Q11 = aB x bB; refill bR <- bA' */ \
    if (C34) { STG(pB0a, pB0b, (CB) + 16384); WAITV4(); } else { WAITV0(); } \
    BAR(); \
    __builtin_amdgcn_s_setprio(1); MM4x2(4, 2, aB, bR); __builtin_amdgcn_s_setprio(0); \
    if (CRF) { _Pragma("unroll") for (int n_ = 0; n_ < 2; ++n_) { \
      int ix = ((CB) ^ 32768) + bBase + n_ * 1024; \
      bR[n_][0] = *(const bf16x8*)&sh[ix]; bR[n_][1] = *(const bf16x8*)&sh[ix ^ 32]; } } \
    BAR(); \
  } while (0)

  f32x4 acc[8][4];
#pragma unroll
  for (int i = 0; i < 8; ++i)
#pragma unroll
    for (int j = 0; j < 4; ++j) acc[i][j] = (f32x4){0.f, 0.f, 0.f, 0.f};

  // prologue: tile0 (4 halves) + tile1 (A0,B0); then read tile0 aA,bA
  STG(pA0a, pA0b,     0);
  STG(pB0a, pB0b, 16384);
  STG(pA1a, pA1b,  8192);
  STG(pB1a, pB1b, 24576);
  STG(pA0a, pA0b, 32768 +     0);
  STG(pB0a, pB0b, 32768 + 16384);
  WAITV4();
  BAR();

  bf16x8 aA[4][2], aB[4][2], bR[2][2];
#pragma unroll
  for (int m = 0; m < 4; ++m) {
    int ix = aBase + m * 1024;
    aA[m][0] = *(const bf16x8*)&sh[ix]; aA[m][1] = *(const bf16x8*)&sh[ix ^ 32];
  }
#pragma unroll
  for (int n = 0; n < 2; ++n) {
    int ix = bBase + n * 1024;
    bR[n][0] = *(const bf16x8*)&sh[ix]; bR[n][1] = *(const bf16x8*)&sh[ix ^ 32];
  }

  for (int i = 0; i < NT / 2; ++i) {        // 36 iters, tiles 2i (buf0), 2i+1 (buf1)
    const bool nl = (i < NT / 2 - 1);       // not-last iteration
    TILE(0,     true, nl, true);            // tile 2i
    TILE(32768, nl,   nl, nl);              // tile 2i+1
  }
#undef STG
#undef MM4x2
#undef TILE

  // epilogue
  const int crow0 = tm * 256 + wm * 128 + g * 4;
  const int ccol0 = tn * 256 + wn * 64 + l15;
#pragma unroll
  for (int mf = 0; mf < 8; ++mf)
#pragma unroll
    for (int n = 0; n < 4; ++n)
#pragma unroll
      for (int q = 0; q < 4; ++q)
        C[(size_t)(crow0 + mf * 16 + q) * D_OUT + ccol0 + n * 16] = acc[mf][n][q];
}

// ---------------------------------------------------------------------------
extern "C" void kernel_launch(void* const* d_in, const int* in_sizes, int n_in,
                              void* d_out, int out_size, void* d_ws, size_t ws_size,
                              hipStream_t stream) {
  const float* x      = (const float*)d_in[0];
  const float* base_w = (const float*)d_in[1];
  const float* gate_w = (const float*)d_in[2];
  const float* lora_A = (const float*)d_in[3];
  const float* lora_B = (const float*)d_in[4];
  float* out = (float*)d_out;

  char* ws = (char*)d_ws;
  u16* xb       = (u16*)ws;                                     // 75,497,472 B
  u16* wb       = (u16*)(ws + 75497472);                        // 37,748,736 B
  u16* la       = (u16*)(ws + 75497472 + 37748736);             //  4,194,304 B
  float* wdense = (float*)(ws + 75497472 + 37748736 + 4194304); //  1,048,576 B

  hipLaunchKernelGGL(k_prep,      dim3(256 + D_OUT + RMOE), dim3(256), 0, stream,
                     x, gate_w, base_w, lora_B, lora_A, wdense, xb, wb, la);
  hipLaunchKernelGGL(k_gemm_ax,   dim3((NTOK/64) * (RMOE/128)),  dim3(256), 0, stream,
                     xb, la, wdense, xb);
  hipLaunchKernelGGL(k_gemm_main, dim3((NTOK/256) * (D_OUT/256)), dim3(512), 0, stream,
                     xb, wb, out);
}

// Round 9
// 396.184 us; speedup vs baseline: 1.2707x; 1.2707x over previous
//
#include <hip/hip_runtime.h>

// MoE-LoRA linear, MI355X (gfx950).
// out = x @ base_w^T + 2.0 * ((x @ lora_A^T) * topk_gate_w) @ lora_B^T
// A_cat[8192][4608] = [ bf16(x) | bf16(SCALING * w_e * (x . lora_A_row)) ]
// W_cat[4096][4608] = [ bf16(base_w) | bf16(lora_B) ]
// Main GEMM: 256x256 tile, 8 waves, 16x16x32 bf16 MFMA, BK=64, dbuf LDS,
// TWO merged phases per K-tile (32 MFMA each) -> 4 barriers/tile (was 8),
// rolled loop (R8's unroll x2 thrashed I-cache: -45% -- never again),
// one-phase-ahead register refills, single counted vmcnt(4) per tile.

#define D_IN   4096
#define D_OUT  4096
#define NTOK   8192      // B*S
#define NE     32
#define RMOE   512       // E*R
#define KCAT   4608      // D_IN + RMOE
#define SCALING 2.0f

typedef unsigned short u16;
typedef __attribute__((ext_vector_type(4)))  float  f32x4;
typedef __attribute__((ext_vector_type(4)))  unsigned short u16x4;
typedef __attribute__((ext_vector_type(8)))  short  bf16x8;

__device__ __forceinline__ u16 f2bf(float f) {
  unsigned u = __float_as_uint(f);
  u += 0x7FFFu + ((u >> 16) & 1u);        // round-to-nearest-even
  return (u16)(u >> 16);
}

__device__ __forceinline__ void gload16(const void* g, void* l) {
  __builtin_amdgcn_global_load_lds(
      (const __attribute__((address_space(1))) unsigned*)g,
      (__attribute__((address_space(3))) unsigned*)l, 16, 0, 0);
}

#define BAR() do { asm volatile("" ::: "memory"); \
                   __builtin_amdgcn_s_barrier();  \
                   asm volatile("" ::: "memory"); } while (0)
#define WAITV6() asm volatile("s_waitcnt vmcnt(6)" ::: "memory")
#define WAITV4() asm volatile("s_waitcnt vmcnt(4)" ::: "memory")
#define WAITV0() asm volatile("s_waitcnt vmcnt(0)" ::: "memory")

// ---------------------------------------------------------------------------
// Kernel 1: fused prep (R6-proven).
//  blocks [0,256):    gating logits GEMM + top-2 + renorm -> wdense,
//                     fused with x -> bf16 into A_cat[:, 0:4096]
//  blocks [256,4864): weight conversion (wb = [base_w|lora_B], la = lora_A)
// ---------------------------------------------------------------------------
#define TT 32
#define KC 256

__global__ __launch_bounds__(256) void k_prep(
    const float* __restrict__ x, const float* __restrict__ gate_w,
    const float* __restrict__ base_w, const float* __restrict__ lora_B,
    const float* __restrict__ lora_A,
    float* __restrict__ wdense, u16* __restrict__ xb,
    u16* __restrict__ wb, u16* __restrict__ la)
{
  __shared__ float smem[2 * TT * KC];       // xs | gs  (64 KiB)
  __shared__ float lgt[TT * 36];
  __shared__ int   e1s[TT]; __shared__ int   e2s[TT];
  __shared__ float w1s[TT]; __shared__ float w2s[TT];
  const int tid = threadIdx.x;

  if (blockIdx.x >= 256) {                  // ---- weight-conversion path ----
    const int bid = blockIdx.x - 256;
    if (bid < D_OUT) {
      const float* src = base_w + (size_t)bid * D_IN;
      u16* dst = wb + (size_t)bid * KCAT;
#pragma unroll
      for (int i = 0; i < 4; ++i) {
        int c = tid + i * 256;
        f32x4 v = ((const f32x4*)src)[c];
        u16x4 h; h[0] = f2bf(v[0]); h[1] = f2bf(v[1]); h[2] = f2bf(v[2]); h[3] = f2bf(v[3]);
        ((u16x4*)dst)[c] = h;
      }
      if (tid < 128) {                      // lora_B row: 512 = 128 x float4
        f32x4 v = ((const f32x4*)(lora_B + (size_t)bid * RMOE))[tid];
        u16x4 h; h[0] = f2bf(v[0]); h[1] = f2bf(v[1]); h[2] = f2bf(v[2]); h[3] = f2bf(v[3]);
        ((u16x4*)(dst + D_IN))[tid] = h;
      }
    } else {
      int r = bid - D_OUT;                  // lora_A row 0..511
      const float* src = lora_A + (size_t)r * D_IN;
      u16* dst = la + (size_t)r * D_IN;
#pragma unroll
      for (int i = 0; i < 4; ++i) {
        int c = tid + i * 256;
        f32x4 v = ((const f32x4*)src)[c];
        u16x4 h; h[0] = f2bf(v[0]); h[1] = f2bf(v[1]); h[2] = f2bf(v[2]); h[3] = f2bf(v[3]);
        ((u16x4*)dst)[c] = h;
      }
    }
    return;
  }

  // ---- gating path ----
  float* xs = smem;
  float* gs = smem + TT * KC;
  const int lane = tid & 63, wave = tid >> 6;
  const int ks = lane >> 4, tg = (lane >> 2) & 3, eg = lane & 3;
  const int row0 = blockIdx.x * TT;
  const int kc0 = wave * 16 + ks * 4;

  float acc[8][8];
#pragma unroll
  for (int t = 0; t < 8; ++t)
#pragma unroll
    for (int e = 0; e < 8; ++e) acc[t][e] = 0.f;

  for (int kt = 0; kt < D_IN / KC; ++kt) {
    __syncthreads();
#pragma unroll
    for (int i = 0; i < 8; ++i) {           // stage x tile + emit bf16 copy
      int c = tid + i * 256;
      int tok = c >> 6, kq = c & 63;
      f32x4 v = ((const f32x4*)(x + (size_t)(row0 + tok) * D_IN + kt * KC))[kq];
      *(f32x4*)&xs[tok * KC + ((kq ^ (tok >> 3)) << 2)] = v;
      u16x4 h;
      h[0] = f2bf(v[0]); h[1] = f2bf(v[1]); h[2] = f2bf(v[2]); h[3] = f2bf(v[3]);
      ((u16x4*)(xb + (size_t)(row0 + tok) * KCAT + kt * KC))[kq] = h;
    }
#pragma unroll
    for (int i = 0; i < 8; ++i) {           // stage gate tile
      int c = tid + i * 256;
      int e = c >> 6, kq = c & 63;
      f32x4 v = ((const f32x4*)(gate_w + (size_t)e * D_IN + kt * KC))[kq];
      *(f32x4*)&gs[e * KC + ((kq ^ (e >> 3)) << 2)] = v;
    }
    __syncthreads();
#pragma unroll
    for (int j = 0; j < 4; ++j) {
      const int Kc = kc0 + j;
      f32x4 xv[8], gv[8];
#pragma unroll
      for (int t = 0; t < 8; ++t)
        xv[t] = *(const f32x4*)&xs[(tg * 8 + t) * KC + ((Kc ^ tg) << 2)];
#pragma unroll
      for (int e = 0; e < 8; ++e)
        gv[e] = *(const f32x4*)&gs[(eg * 8 + e) * KC + ((Kc ^ eg) << 2)];
#pragma unroll
      for (int t = 0; t < 8; ++t)
#pragma unroll
        for (int e = 0; e < 8; ++e)
#pragma unroll
          for (int m = 0; m < 4; ++m)
            acc[t][e] += xv[t][m] * gv[e][m];
    }
  }

#pragma unroll
  for (int t = 0; t < 8; ++t)
#pragma unroll
    for (int e = 0; e < 8; ++e) {
      float v = acc[t][e];
      v += __shfl_xor(v, 16);
      v += __shfl_xor(v, 32);
      acc[t][e] = v;
    }
  __syncthreads();
  float* red = smem;
  if (ks == 0) {
#pragma unroll
    for (int t = 0; t < 8; ++t)
#pragma unroll
      for (int e4 = 0; e4 < 8; e4 += 4) {
        f32x4 v = { acc[t][e4], acc[t][e4 + 1], acc[t][e4 + 2], acc[t][e4 + 3] };
        *(f32x4*)&red[(wave * 16 + tg * 4 + eg) * 64 + t * 8 + e4] = v;
      }
  }
  __syncthreads();
  {
    int tok = tid >> 3, e4 = (tid & 7) << 2;
    f32x4 s = {0.f, 0.f, 0.f, 0.f};
#pragma unroll
    for (int w = 0; w < 4; ++w)
      s += *(const f32x4*)&red[(w * 16 + (tok >> 3) * 4 + (e4 >> 3)) * 64 + (tok & 7) * 8 + (e4 & 7)];
    *(f32x4*)&lgt[tok * 36 + e4] = s;
  }
  __syncthreads();
  if (tid < TT) {
    float l1 = -1e30f; int e1 = 0;
    for (int e = 0; e < NE; ++e) { float v = lgt[tid * 36 + e]; if (v > l1) { l1 = v; e1 = e; } }
    float l2 = -1e30f; int e2 = 0;
    for (int e = 0; e < NE; ++e) { if (e == e1) continue; float v = lgt[tid * 36 + e]; if (v > l2) { l2 = v; e2 = e; } }
    float t = __expf(l2 - l1);
    float w2 = t / (1.f + t);
    e1s[tid] = e1; e2s[tid] = e2; w1s[tid] = 1.f - w2; w2s[tid] = w2;
  }
  __syncthreads();
#pragma unroll
  for (int i = 0; i < 4; ++i) {
    int c = tid + i * 256;
    int tok = c >> 5, e = c & 31;
    float v = (e == e1s[tok]) ? w1s[tok] : (e == e2s[tok]) ? w2s[tok] : 0.f;
    wdense[(size_t)(row0 + tok) * NE + e] = v;
  }
}

// ---------------------------------------------------------------------------
// Kernel 2: ax GEMM  (A_cat[:, :4096] @ lora_A^T) * w * SCALING -> A_cat tail
// 64x128 tile, 512 blocks, BK=64, 4 waves (1Mx4N), 3-buffer pipeline 2 ahead,
// vmcnt(6), XOR swizzle.  (R6-proven)
// ---------------------------------------------------------------------------
__global__ __launch_bounds__(256) void k_gemm_ax(
    const u16* __restrict__ A, const u16* __restrict__ La,
    const float* __restrict__ wdense, u16* __restrict__ xb)
{
  __shared__ u16 sh[36864];                 // 3 bufs x (As 4096 | Bs 8192)
  const int nwg = gridDim.x;                // 512 (div by 8 -> bijective)
  int bid = blockIdx.x;
  int wg = (bid & 7) * (nwg >> 3) + (bid >> 3);
  const int tm = wg >> 2, tn = wg & 3;      // 128 m-tiles, 4 n-tiles
  const int tid = threadIdx.x;
  const int lane = tid & 63, wn = tid >> 6; // 4 waves split N
  const int l15 = lane & 15, g = lane >> 4;
  const int row0 = tm * 64, col0 = tn * 128;

  size_t offA[2], offB[4]; int dA[2], dB[4];
#pragma unroll
  for (int i = 0; i < 2; ++i) {
    int c = tid + i * 256;
    int r = c >> 3, s = (c & 7) ^ (r & 7);
    offA[i] = (size_t)(row0 + r) * KCAT + s * 8;
    dA[i] = c * 8;
  }
#pragma unroll
  for (int i = 0; i < 4; ++i) {
    int c = tid + i * 256;
    int r = c >> 3, s = (c & 7) ^ (r & 7);
    offB[i] = (size_t)(col0 + r) * D_IN + s * 8;
    dB[i] = c * 8;
  }

#define STGAX(b, kt) do { \
    _Pragma("unroll") for (int i = 0; i < 2; ++i) \
      gload16(A  + offA[i] + (size_t)(kt) * 64, &sh[(b) * 12288 + dA[i]]); \
    _Pragma("unroll") for (int i = 0; i < 4; ++i) \
      gload16(La + offB[i] + (size_t)(kt) * 64, &sh[(b) * 12288 + 4096 + dB[i]]); } while (0)

  f32x4 acc[4][2];
#pragma unroll
  for (int i = 0; i < 4; ++i)
#pragma unroll
    for (int j = 0; j < 2; ++j) acc[i][j] = (f32x4){0.f, 0.f, 0.f, 0.f};

  STGAX(0, 0);
  STGAX(1, 1);
  WAITV6();                                 // tile0 landed
  BAR();

  const int swz = (g ^ (l15 & 7)) * 8;
  for (int kt = 0; kt < D_IN / 64; ++kt) {  // 64 tiles
    if (kt + 2 < D_IN / 64) STGAX((kt + 2) % 3, kt + 2);
    const u16* As_ = &sh[(kt % 3) * 12288];
    const u16* Bs_ = &sh[(kt % 3) * 12288 + 4096];
    bf16x8 af[4][2], bfr[2][2];
#pragma unroll
    for (int i = 0; i < 4; ++i) {
      int ixa = (i * 16 + l15) * 64 + swz;
      af[i][0] = *(const bf16x8*)&As_[ixa]; af[i][1] = *(const bf16x8*)&As_[ixa ^ 32];
    }
#pragma unroll
    for (int j = 0; j < 2; ++j) {
      int ixb = (wn * 32 + j * 16 + l15) * 64 + swz;
      bfr[j][0] = *(const bf16x8*)&Bs_[ixb]; bfr[j][1] = *(const bf16x8*)&Bs_[ixb ^ 32];
    }
    __builtin_amdgcn_s_setprio(1);
#pragma unroll
    for (int i = 0; i < 4; ++i)
#pragma unroll
      for (int j = 0; j < 2; ++j)
#pragma unroll
        for (int kk = 0; kk < 2; ++kk)
          acc[i][j] = __builtin_amdgcn_mfma_f32_16x16x32_bf16(af[i][kk], bfr[j][kk], acc[i][j], 0, 0, 0);
    __builtin_amdgcn_s_setprio(0);
    if (kt >= D_IN / 64 - 2) WAITV0(); else WAITV6();
    BAR();
  }
#undef STGAX

  // epilogue: scale by gate weight, SCALING, store bf16 to A_cat tail
#pragma unroll
  for (int i = 0; i < 4; ++i) {
    int rbase = row0 + i * 16 + (g << 2);
#pragma unroll
    for (int j = 0; j < 2; ++j) {
      int cb = col0 + wn * 32 + j * 16 + l15;
#pragma unroll
      for (int q = 0; q < 4; ++q) {
        int trow = rbase + q;
        float wgt = wdense[(size_t)trow * NE + (cb >> 4)];
        xb[(size_t)trow * KCAT + D_IN + cb] = f2bf(acc[i][j][q] * wgt * SCALING);
      }
    }
  }
}

// ---------------------------------------------------------------------------
// Kernel 3: main GEMM  out = A_cat @ W_cat^T  (M=8192, N=4096, K=4608)
// 256x256 tile, 8 waves (2Mx4N), 16x16x32 bf16 MFMA, BK=64, dbuf 128 KiB LDS.
// TWO merged phases per K-tile (4 barriers/tile):
//  Phase A: stage A1,B1(u+1); read aB; MFMA Q00+Q10 (32); refill bR<-bB
//  Phase B: stage A0,B0(u+2); WAITV4; MFMA Q01+Q11 (32); refill aA,bR<-next
// LDS hazard check: each region's last ds_read is >=2 barriers before its
// overwrite; single WAITV4 drains tile u+1's 4 halves right before first use.
// ---------------------------------------------------------------------------
#define NT (KCAT / 64)    // 72

__global__ __launch_bounds__(512, 2) void k_gemm_main(
    const u16* __restrict__ A, const u16* __restrict__ Bw, float* __restrict__ C)
{
  // [buf:2][op A|B:2][half:2][128 rows][64 cols] u16 = 128 KiB
  __shared__ u16 sh[65536];

  const int tid  = threadIdx.x;
  const int lane = tid & 63;
  const int wv   = tid >> 6;            // 0..7
  const int wm   = wv >> 2;             // 0..1
  const int wn   = wv & 3;              // 0..3
  const int l15  = lane & 15, g = lane >> 4;

  // T1: bijective XCD swizzle (512 blocks, 512 % 8 == 0)
  const int nwg = gridDim.x;
  int bid = blockIdx.x;
  int wg = (bid & 7) * (nwg >> 3) + (bid >> 3);
  const int tn = wg & 15, tm = wg >> 4; // 16 n-tiles, 32 m-tiles

  // LDS read addressing (T2 swizzle: slot ^= row&7; row&7 == l15&7)
  const int rsw   = (g ^ (l15 & 7)) * 8;
  const int aBase = l15 * 64 + rsw;
  const int bBase = ((wn & 1) * 64 + l15) * 64 + rsw;

  // staging: pre-swizzled global sources, linear gload_lds dests
  const int c0 = tid, c1 = tid + 512;
  const int r0s = c0 >> 3, s0s = (c0 & 7) ^ (r0s & 7);
  const int r1s = c1 >> 3, s1s = (c1 & 7) ^ (r1s & 7);
  const size_t offc0 = (size_t)r0s * KCAT + s0s * 8;
  const size_t offc1 = (size_t)r1s * KCAT + s1s * 8;
  const u16* pA0a = A  + (size_t)(tm * 256 +   0) * KCAT + offc0;
  const u16* pA0b = A  + (size_t)(tm * 256 +   0) * KCAT + offc1;
  const u16* pA1a = A  + (size_t)(tm * 256 + 128) * KCAT + offc0;
  const u16* pA1b = A  + (size_t)(tm * 256 + 128) * KCAT + offc1;
  const u16* pB0a = Bw + (size_t)(tn * 256 +   0) * KCAT + offc0;
  const u16* pB0b = Bw + (size_t)(tn * 256 +   0) * KCAT + offc1;
  const u16* pB1a = Bw + (size_t)(tn * 256 + 128) * KCAT + offc0;
  const u16* pB1b = Bw + (size_t)(tn * 256 + 128) * KCAT + offc1;
  const int d0 = c0 * 8, d1 = c1 * 8;

#define STG(pa, pb, base) do { \
    gload16((pa), &sh[(base) + d0]); \
    gload16((pb), &sh[(base) + d1]); \
    (pa) += 64; (pb) += 64; } while (0)

#define MM4x2(MO, NO, AF, BF) do { \
    _Pragma("unroll") for (int m_ = 0; m_ < 4; ++m_) \
    _Pragma("unroll") for (int n_ = 0; n_ < 2; ++n_) \
    _Pragma("unroll") for (int kk_ = 0; kk_ < 2; ++kk_) \
      acc[m_ + (MO)][n_ + (NO)] = __builtin_amdgcn_mfma_f32_16x16x32_bf16( \
          AF[m_][kk_], BF[n_][kk_], acc[m_ + (MO)][n_ + (NO)], 0, 0, 0); } while (0)

  f32x4 acc[8][4];
#pragma unroll
  for (int i = 0; i < 8; ++i)
#pragma unroll
    for (int j = 0; j < 4; ++j) acc[i][j] = (f32x4){0.f, 0.f, 0.f, 0.f};

  // prologue: tile0 (4 halves) + tile1 (A0,B0); then read tile0 aA,bA
  STG(pA0a, pA0b,     0);
  STG(pB0a, pB0b, 16384);
  STG(pA1a, pA1b,  8192);
  STG(pB1a, pB1b, 24576);
  STG(pA0a, pA0b, 32768 +     0);
  STG(pB0a, pB0b, 32768 + 16384);
  WAITV4();
  BAR();

  bf16x8 aA[4][2], aB[4][2], bR[2][2];
  {
    const int shA = (wm << 13);
    const int shB = 16384 + ((wn >> 1) << 13);
#pragma unroll
    for (int m = 0; m < 4; ++m) {
      int ix = shA + aBase + m * 1024;
      aA[m][0] = *(const bf16x8*)&sh[ix]; aA[m][1] = *(const bf16x8*)&sh[ix ^ 32];
    }
#pragma unroll
    for (int n = 0; n < 2; ++n) {
      int ix = shB + bBase + n * 1024;
      bR[n][0] = *(const bf16x8*)&sh[ix]; bR[n][1] = *(const bf16x8*)&sh[ix ^ 32];
    }
  }

  for (int u = 0; u < NT; ++u) {
    const int cb = (u & 1) << 15;
    const int nb = cb ^ 32768;
    const int shA  = cb + (wm << 13);
    const int shB  = cb + 16384 + ((wn >> 1) << 13);
    const int shAn = nb + (wm << 13);
    const int shBn = nb + 16384 + ((wn >> 1) << 13);

    // ---- Phase A: stage A1,B1(u+1); read aB; MFMA Q00+Q10; refill bR<-bB
    if (u < NT - 1) {
      STG(pA1a, pA1b, nb + 8192);
      STG(pB1a, pB1b, nb + 24576);
    }
#pragma unroll
    for (int m = 0; m < 4; ++m) {
      int ix = shA + aBase + (m + 4) * 1024;
      aB[m][0] = *(const bf16x8*)&sh[ix]; aB[m][1] = *(const bf16x8*)&sh[ix ^ 32];
    }
    BAR();
    __builtin_amdgcn_s_setprio(1);
    MM4x2(0, 0, aA, bR);
    MM4x2(4, 0, aB, bR);
    __builtin_amdgcn_s_setprio(0);
#pragma unroll
    for (int n = 0; n < 2; ++n) {
      int ix = shB + bBase + (n + 2) * 1024;
      bR[n][0] = *(const bf16x8*)&sh[ix]; bR[n][1] = *(const bf16x8*)&sh[ix ^ 32];
    }
    BAR();

    // ---- Phase B: stage A0,B0(u+2); counted wait; MFMA Q01+Q11; refill next
    if (u < NT - 2) {
      STG(pA0a, pA0b, cb + 0);
      STG(pB0a, pB0b, cb + 16384);
      WAITV4();
    } else {
      WAITV0();
    }
    BAR();
    __builtin_amdgcn_s_setprio(1);
    MM4x2(0, 2, aA, bR);
    MM4x2(4, 2, aB, bR);
    __builtin_amdgcn_s_setprio(0);
    if (u < NT - 1) {
#pragma unroll
      for (int m = 0; m < 4; ++m) {
        int ix = shAn + aBase + m * 1024;
        aA[m][0] = *(const bf16x8*)&sh[ix]; aA[m][1] = *(const bf16x8*)&sh[ix ^ 32];
      }
#pragma unroll
      for (int n = 0; n < 2; ++n) {
        int ix = shBn + bBase + n * 1024;
        bR[n][0] = *(const bf16x8*)&sh[ix]; bR[n][1] = *(const bf16x8*)&sh[ix ^ 32];
      }
    }
    BAR();
  }
#undef STG
#undef MM4x2

  // epilogue
  const int crow0 = tm * 256 + wm * 128 + g * 4;
  const int ccol0 = tn * 256 + wn * 64 + l15;
#pragma unroll
  for (int mf = 0; mf < 8; ++mf)
#pragma unroll
    for (int n = 0; n < 4; ++n)
#pragma unroll
      for (int q = 0; q < 4; ++q)
        C[(size_t)(crow0 + mf * 16 + q) * D_OUT + ccol0 + n * 16] = acc[mf][n][q];
}

// ---------------------------------------------------------------------------
extern "C" void kernel_launch(void* const* d_in, const int* in_sizes, int n_in,
                              void* d_out, int out_size, void* d_ws, size_t ws_size,
                              hipStream_t stream) {
  const float* x      = (const float*)d_in[0];
  const float* base_w = (const float*)d_in[1];
  const float* gate_w = (const float*)d_in[2];
  const float* lora_A = (const float*)d_in[3];
  const float* lora_B = (const float*)d_in[4];
  float* out = (float*)d_out;

  char* ws = (char*)d_ws;
  u16* xb       = (u16*)ws;                                     // 75,497,472 B
  u16* wb       = (u16*)(ws + 75497472);                        // 37,748,736 B
  u16* la       = (u16*)(ws + 75497472 + 37748736);             //  4,194,304 B
  float* wdense = (float*)(ws + 75497472 + 37748736 + 4194304); //  1,048,576 B

  hipLaunchKernelGGL(k_prep,      dim3(256 + D_OUT + RMOE), dim3(256), 0, stream,
                     x, gate_w, base_w, lora_B, lora_A, wdense, xb, wb, la);
  hipLaunchKernelGGL(k_gemm_ax,   dim3((NTOK/64) * (RMOE/128)),  dim3(256), 0, stream,
                     xb, la, wdense, xb);
  hipLaunchKernelGGL(k_gemm_main, dim3((NTOK/256) * (D_OUT/256)), dim3(512), 0, stream,
                     xb, wb, out);
}

// Round 10
// 390.315 us; speedup vs baseline: 1.2898x; 1.0150x over previous
//
#include <hip/hip_runtime.h>

// MoE-LoRA linear, MI355X (gfx950).
// out = x @ base_w^T + 2.0 * ((x @ lora_A^T) * topk_gate_w) @ lora_B^T
// A_cat[8192][4608] = [ bf16(x) | bf16(SCALING * w_e * (x . lora_A_row)) ]
// W_cat[4096][4608] = [ bf16(base_w) | bf16(lora_B) ]
// Main GEMM: R7-proven 256x256-tile 8-wave 4-phase counted-vmcnt schedule
// (264 us, MfmaUtil 52%; R8 unroll and R9 barrier-merge both regressed).
// Aux: gating kernel (LDS-heavy) split from weight conversion (LDS-free
// streaming) so wconv runs at full occupancy instead of 2 blocks/CU.

#define D_IN   4096
#define D_OUT  4096
#define NTOK   8192      // B*S
#define NE     32
#define RMOE   512       // E*R
#define KCAT   4608      // D_IN + RMOE
#define SCALING 2.0f

typedef unsigned short u16;
typedef __attribute__((ext_vector_type(4)))  float  f32x4;
typedef __attribute__((ext_vector_type(4)))  unsigned short u16x4;
typedef __attribute__((ext_vector_type(8)))  short  bf16x8;

__device__ __forceinline__ u16 f2bf(float f) {
  unsigned u = __float_as_uint(f);
  u += 0x7FFFu + ((u >> 16) & 1u);        // round-to-nearest-even
  return (u16)(u >> 16);
}

__device__ __forceinline__ void gload16(const void* g, void* l) {
  __builtin_amdgcn_global_load_lds(
      (const __attribute__((address_space(1))) unsigned*)g,
      (__attribute__((address_space(3))) unsigned*)l, 16, 0, 0);
}

#define BAR() do { asm volatile("" ::: "memory"); \
                   __builtin_amdgcn_s_barrier();  \
                   asm volatile("" ::: "memory"); } while (0)
#define WAITV6() asm volatile("s_waitcnt vmcnt(6)" ::: "memory")
#define WAITV4() asm volatile("s_waitcnt vmcnt(4)" ::: "memory")
#define WAITV0() asm volatile("s_waitcnt vmcnt(0)" ::: "memory")

// ---------------------------------------------------------------------------
// Kernel 1: gating logits GEMM + top-2 + renorm -> wdense, fused with
//           x -> bf16 into A_cat[:, 0:4096].  256 blocks.
// ---------------------------------------------------------------------------
#define TT 32
#define KC 256

__global__ __launch_bounds__(256) void k_gate(
    const float* __restrict__ x, const float* __restrict__ gate_w,
    float* __restrict__ wdense, u16* __restrict__ xb)
{
  __shared__ float smem[2 * TT * KC];       // xs | gs  (64 KiB)
  __shared__ float lgt[TT * 36];
  __shared__ int   e1s[TT]; __shared__ int   e2s[TT];
  __shared__ float w1s[TT]; __shared__ float w2s[TT];
  const int tid = threadIdx.x;

  float* xs = smem;
  float* gs = smem + TT * KC;
  const int lane = tid & 63, wave = tid >> 6;
  const int ks = lane >> 4, tg = (lane >> 2) & 3, eg = lane & 3;
  const int row0 = blockIdx.x * TT;
  const int kc0 = wave * 16 + ks * 4;

  float acc[8][8];
#pragma unroll
  for (int t = 0; t < 8; ++t)
#pragma unroll
    for (int e = 0; e < 8; ++e) acc[t][e] = 0.f;

  for (int kt = 0; kt < D_IN / KC; ++kt) {
    __syncthreads();
#pragma unroll
    for (int i = 0; i < 8; ++i) {           // stage x tile + emit bf16 copy
      int c = tid + i * 256;
      int tok = c >> 6, kq = c & 63;
      f32x4 v = ((const f32x4*)(x + (size_t)(row0 + tok) * D_IN + kt * KC))[kq];
      *(f32x4*)&xs[tok * KC + ((kq ^ (tok >> 3)) << 2)] = v;
      u16x4 h;
      h[0] = f2bf(v[0]); h[1] = f2bf(v[1]); h[2] = f2bf(v[2]); h[3] = f2bf(v[3]);
      ((u16x4*)(xb + (size_t)(row0 + tok) * KCAT + kt * KC))[kq] = h;
    }
#pragma unroll
    for (int i = 0; i < 8; ++i) {           // stage gate tile
      int c = tid + i * 256;
      int e = c >> 6, kq = c & 63;
      f32x4 v = ((const f32x4*)(gate_w + (size_t)e * D_IN + kt * KC))[kq];
      *(f32x4*)&gs[e * KC + ((kq ^ (e >> 3)) << 2)] = v;
    }
    __syncthreads();
#pragma unroll
    for (int j = 0; j < 4; ++j) {
      const int Kc = kc0 + j;
      f32x4 xv[8], gv[8];
#pragma unroll
      for (int t = 0; t < 8; ++t)
        xv[t] = *(const f32x4*)&xs[(tg * 8 + t) * KC + ((Kc ^ tg) << 2)];
#pragma unroll
      for (int e = 0; e < 8; ++e)
        gv[e] = *(const f32x4*)&gs[(eg * 8 + e) * KC + ((Kc ^ eg) << 2)];
#pragma unroll
      for (int t = 0; t < 8; ++t)
#pragma unroll
        for (int e = 0; e < 8; ++e)
#pragma unroll
          for (int m = 0; m < 4; ++m)
            acc[t][e] += xv[t][m] * gv[e][m];
    }
  }

#pragma unroll
  for (int t = 0; t < 8; ++t)
#pragma unroll
    for (int e = 0; e < 8; ++e) {
      float v = acc[t][e];
      v += __shfl_xor(v, 16);
      v += __shfl_xor(v, 32);
      acc[t][e] = v;
    }
  __syncthreads();
  float* red = smem;
  if (ks == 0) {
#pragma unroll
    for (int t = 0; t < 8; ++t)
#pragma unroll
      for (int e4 = 0; e4 < 8; e4 += 4) {
        f32x4 v = { acc[t][e4], acc[t][e4 + 1], acc[t][e4 + 2], acc[t][e4 + 3] };
        *(f32x4*)&red[(wave * 16 + tg * 4 + eg) * 64 + t * 8 + e4] = v;
      }
  }
  __syncthreads();
  {
    int tok = tid >> 3, e4 = (tid & 7) << 2;
    f32x4 s = {0.f, 0.f, 0.f, 0.f};
#pragma unroll
    for (int w = 0; w < 4; ++w)
      s += *(const f32x4*)&red[(w * 16 + (tok >> 3) * 4 + (e4 >> 3)) * 64 + (tok & 7) * 8 + (e4 & 7)];
    *(f32x4*)&lgt[tok * 36 + e4] = s;
  }
  __syncthreads();
  if (tid < TT) {
    float l1 = -1e30f; int e1 = 0;
    for (int e = 0; e < NE; ++e) { float v = lgt[tid * 36 + e]; if (v > l1) { l1 = v; e1 = e; } }
    float l2 = -1e30f; int e2 = 0;
    for (int e = 0; e < NE; ++e) { if (e == e1) continue; float v = lgt[tid * 36 + e]; if (v > l2) { l2 = v; e2 = e; } }
    float t = __expf(l2 - l1);
    float w2 = t / (1.f + t);
    e1s[tid] = e1; e2s[tid] = e2; w1s[tid] = 1.f - w2; w2s[tid] = w2;
  }
  __syncthreads();
#pragma unroll
  for (int i = 0; i < 4; ++i) {
    int c = tid + i * 256;
    int tok = c >> 5, e = c & 31;
    float v = (e == e1s[tok]) ? w1s[tok] : (e == e2s[tok]) ? w2s[tok] : 0.f;
    wdense[(size_t)(row0 + tok) * NE + e] = v;
  }
}

// ---------------------------------------------------------------------------
// Kernel 2: weight conversion to bf16 (wb = [base_w|lora_B], la = lora_A).
// LDS-free pure streaming -> full occupancy (unlike fused-in-k_prep variant
// whose 66 KiB LDS capped ALL blocks at 2/CU).
// ---------------------------------------------------------------------------
__global__ __launch_bounds__(256) void k_wconv(
    const float* __restrict__ base_w, const float* __restrict__ lora_B,
    const float* __restrict__ lora_A, u16* __restrict__ wb, u16* __restrict__ la)
{
  const int bid = blockIdx.x, tid = threadIdx.x;
  if (bid < D_OUT) {
    const float* src = base_w + (size_t)bid * D_IN;
    u16* dst = wb + (size_t)bid * KCAT;
#pragma unroll
    for (int i = 0; i < 4; ++i) {
      int c = tid + i * 256;
      f32x4 v = ((const f32x4*)src)[c];
      u16x4 h; h[0] = f2bf(v[0]); h[1] = f2bf(v[1]); h[2] = f2bf(v[2]); h[3] = f2bf(v[3]);
      ((u16x4*)dst)[c] = h;
    }
    if (tid < 128) {                        // lora_B row: 512 = 128 x float4
      f32x4 v = ((const f32x4*)(lora_B + (size_t)bid * RMOE))[tid];
      u16x4 h; h[0] = f2bf(v[0]); h[1] = f2bf(v[1]); h[2] = f2bf(v[2]); h[3] = f2bf(v[3]);
      ((u16x4*)(dst + D_IN))[tid] = h;
    }
  } else {
    int r = bid - D_OUT;                    // lora_A row 0..511
    const float* src = lora_A + (size_t)r * D_IN;
    u16* dst = la + (size_t)r * D_IN;
#pragma unroll
    for (int i = 0; i < 4; ++i) {
      int c = tid + i * 256;
      f32x4 v = ((const f32x4*)src)[c];
      u16x4 h; h[0] = f2bf(v[0]); h[1] = f2bf(v[1]); h[2] = f2bf(v[2]); h[3] = f2bf(v[3]);
      ((u16x4*)dst)[c] = h;
    }
  }
}

// ---------------------------------------------------------------------------
// Kernel 3: ax GEMM  (A_cat[:, :4096] @ lora_A^T) * w * SCALING -> A_cat tail
// 64x128 tile, 512 blocks, BK=64, 4 waves (1Mx4N), 3-buffer pipeline 2 ahead,
// vmcnt(6), XOR swizzle.  (R6-proven)
// ---------------------------------------------------------------------------
__global__ __launch_bounds__(256) void k_gemm_ax(
    const u16* __restrict__ A, const u16* __restrict__ La,
    const float* __restrict__ wdense, u16* __restrict__ xb)
{
  __shared__ u16 sh[36864];                 // 3 bufs x (As 4096 | Bs 8192)
  const int nwg = gridDim.x;                // 512 (div by 8 -> bijective)
  int bid = blockIdx.x;
  int wg = (bid & 7) * (nwg >> 3) + (bid >> 3);
  const int tm = wg >> 2, tn = wg & 3;      // 128 m-tiles, 4 n-tiles
  const int tid = threadIdx.x;
  const int lane = tid & 63, wn = tid >> 6; // 4 waves split N
  const int l15 = lane & 15, g = lane >> 4;
  const int row0 = tm * 64, col0 = tn * 128;

  size_t offA[2], offB[4]; int dA[2], dB[4];
#pragma unroll
  for (int i = 0; i < 2; ++i) {
    int c = tid + i * 256;
    int r = c >> 3, s = (c & 7) ^ (r & 7);
    offA[i] = (size_t)(row0 + r) * KCAT + s * 8;
    dA[i] = c * 8;
  }
#pragma unroll
  for (int i = 0; i < 4; ++i) {
    int c = tid + i * 256;
    int r = c >> 3, s = (c & 7) ^ (r & 7);
    offB[i] = (size_t)(col0 + r) * D_IN + s * 8;
    dB[i] = c * 8;
  }

#define STGAX(b, kt) do { \
    _Pragma("unroll") for (int i = 0; i < 2; ++i) \
      gload16(A  + offA[i] + (size_t)(kt) * 64, &sh[(b) * 12288 + dA[i]]); \
    _Pragma("unroll") for (int i = 0; i < 4; ++i) \
      gload16(La + offB[i] + (size_t)(kt) * 64, &sh[(b) * 12288 + 4096 + dB[i]]); } while (0)

  f32x4 acc[4][2];
#pragma unroll
  for (int i = 0; i < 4; ++i)
#pragma unroll
    for (int j = 0; j < 2; ++j) acc[i][j] = (f32x4){0.f, 0.f, 0.f, 0.f};

  STGAX(0, 0);
  STGAX(1, 1);
  WAITV6();                                 // tile0 landed
  BAR();

  const int swz = (g ^ (l15 & 7)) * 8;
  for (int kt = 0; kt < D_IN / 64; ++kt) {  // 64 tiles
    if (kt + 2 < D_IN / 64) STGAX((kt + 2) % 3, kt + 2);
    const u16* As_ = &sh[(kt % 3) * 12288];
    const u16* Bs_ = &sh[(kt % 3) * 12288 + 4096];
    bf16x8 af[4][2], bfr[2][2];
#pragma unroll
    for (int i = 0; i < 4; ++i) {
      int ixa = (i * 16 + l15) * 64 + swz;
      af[i][0] = *(const bf16x8*)&As_[ixa]; af[i][1] = *(const bf16x8*)&As_[ixa ^ 32];
    }
#pragma unroll
    for (int j = 0; j < 2; ++j) {
      int ixb = (wn * 32 + j * 16 + l15) * 64 + swz;
      bfr[j][0] = *(const bf16x8*)&Bs_[ixb]; bfr[j][1] = *(const bf16x8*)&Bs_[ixb ^ 32];
    }
    __builtin_amdgcn_s_setprio(1);
#pragma unroll
    for (int i = 0; i < 4; ++i)
#pragma unroll
      for (int j = 0; j < 2; ++j)
#pragma unroll
        for (int kk = 0; kk < 2; ++kk)
          acc[i][j] = __builtin_amdgcn_mfma_f32_16x16x32_bf16(af[i][kk], bfr[j][kk], acc[i][j], 0, 0, 0);
    __builtin_amdgcn_s_setprio(0);
    if (kt >= D_IN / 64 - 2) WAITV0(); else WAITV6();
    BAR();
  }
#undef STGAX

  // epilogue: scale by gate weight, SCALING, store bf16 to A_cat tail
#pragma unroll
  for (int i = 0; i < 4; ++i) {
    int rbase = row0 + i * 16 + (g << 2);
#pragma unroll
    for (int j = 0; j < 2; ++j) {
      int cb = col0 + wn * 32 + j * 16 + l15;
#pragma unroll
      for (int q = 0; q < 4; ++q) {
        int trow = rbase + q;
        float wgt = wdense[(size_t)trow * NE + (cb >> 4)];
        xb[(size_t)trow * KCAT + D_IN + cb] = f2bf(acc[i][j][q] * wgt * SCALING);
      }
    }
  }
}

// ---------------------------------------------------------------------------
// Kernel 4: main GEMM  out = A_cat @ W_cat^T  (M=8192, N=4096, K=4608)
// R7-proven: 256x256 tile, 8 waves (2Mx4N), 16x16x32 bf16 MFMA, BK=64,
// dbuf 128 KiB LDS, 4 phases/K-tile, counted vmcnt(4) x2, XOR-swizzled LDS,
// one-phase-ahead fragment reads.
// ---------------------------------------------------------------------------
#define NT (KCAT / 64)    // 72

__global__ __launch_bounds__(512, 2) void k_gemm_main(
    const u16* __restrict__ A, const u16* __restrict__ Bw, float* __restrict__ C)
{
  // [buf:2][op A|B:2][half:2][128 rows][64 cols] u16 = 128 KiB
  __shared__ u16 sh[65536];

  const int tid  = threadIdx.x;
  const int lane = tid & 63;
  const int wv   = tid >> 6;            // 0..7
  const int wm   = wv >> 2;             // 0..1
  const int wn   = wv & 3;              // 0..3
  const int l15  = lane & 15, g = lane >> 4;

  // T1: bijective XCD swizzle (512 blocks, 512 % 8 == 0)
  const int nwg = gridDim.x;
  int bid = blockIdx.x;
  int wg = (bid & 7) * (nwg >> 3) + (bid >> 3);
  const int tn = wg & 15, tm = wg >> 4; // 16 n-tiles, 32 m-tiles

  // LDS read addressing (T2 swizzle: slot ^= row&7; row&7 == l15&7)
  const int rsw   = (g ^ (l15 & 7)) * 8;
  const int aBase = l15 * 64 + rsw;
  const int bBase = ((wn & 1) * 64 + l15) * 64 + rsw;

  // staging: pre-swizzled global sources, linear gload_lds dests
  const int c0 = tid, c1 = tid + 512;
  const int r0s = c0 >> 3, s0s = (c0 & 7) ^ (r0s & 7);
  const int r1s = c1 >> 3, s1s = (c1 & 7) ^ (r1s & 7);
  const size_t offc0 = (size_t)r0s * KCAT + s0s * 8;
  const size_t offc1 = (size_t)r1s * KCAT + s1s * 8;
  const u16* pA0a = A  + (size_t)(tm * 256 +   0) * KCAT + offc0;
  const u16* pA0b = A  + (size_t)(tm * 256 +   0) * KCAT + offc1;
  const u16* pA1a = A  + (size_t)(tm * 256 + 128) * KCAT + offc0;
  const u16* pA1b = A  + (size_t)(tm * 256 + 128) * KCAT + offc1;
  const u16* pB0a = Bw + (size_t)(tn * 256 +   0) * KCAT + offc0;
  const u16* pB0b = Bw + (size_t)(tn * 256 +   0) * KCAT + offc1;
  const u16* pB1a = Bw + (size_t)(tn * 256 + 128) * KCAT + offc0;
  const u16* pB1b = Bw + (size_t)(tn * 256 + 128) * KCAT + offc1;
  const int d0 = c0 * 8, d1 = c1 * 8;

#define STG(pa, pb, base) do { \
    gload16((pa), &sh[(base) + d0]); \
    gload16((pb), &sh[(base) + d1]); \
    (pa) += 64; (pb) += 64; } while (0)

#define MM4x2(MO, NO, AF, BF) do { \
    _Pragma("unroll") for (int m_ = 0; m_ < 4; ++m_) \
    _Pragma("unroll") for (int n_ = 0; n_ < 2; ++n_) \
    _Pragma("unroll") for (int kk_ = 0; kk_ < 2; ++kk_) \
      acc[m_ + (MO)][n_ + (NO)] = __builtin_amdgcn_mfma_f32_16x16x32_bf16( \
          AF[m_][kk_], BF[n_][kk_], acc[m_ + (MO)][n_ + (NO)], 0, 0, 0); } while (0)

  f32x4 acc[8][4];
#pragma unroll
  for (int i = 0; i < 8; ++i)
#pragma unroll
    for (int j = 0; j < 4; ++j) acc[i][j] = (f32x4){0.f, 0.f, 0.f, 0.f};

  // prologue: tile0 (4 halves) + tile1 (A0,B0); then read tile0 aA,bA
  STG(pA0a, pA0b,     0);
  STG(pB0a, pB0b, 16384);
  STG(pA1a, pA1b,  8192);
  STG(pB1a, pB1b, 24576);
  STG(pA0a, pA0b, 32768 +     0);
  STG(pB0a, pB0b, 32768 + 16384);
  WAITV4();
  BAR();

  bf16x8 aA[4][2], aB[4][2], bR[2][2];
  {
    const int shA = (wm << 13);
    const int shB = 16384 + ((wn >> 1) << 13);
#pragma unroll
    for (int m = 0; m < 4; ++m) {
      int ix = shA + aBase + m * 1024;
      aA[m][0] = *(const bf16x8*)&sh[ix]; aA[m][1] = *(const bf16x8*)&sh[ix ^ 32];
    }
#pragma unroll
    for (int n = 0; n < 2; ++n) {
      int ix = shB + bBase + n * 1024;
      bR[n][0] = *(const bf16x8*)&sh[ix]; bR[n][1] = *(const bf16x8*)&sh[ix ^ 32];
    }
  }

  for (int u = 0; u < NT; ++u) {
    const int cb = (u & 1) << 15;
    const int nb = cb ^ 32768;
    const int shA  = cb + (wm << 13);
    const int shB  = cb + 16384 + ((wn >> 1) << 13);
    const int shAn = nb + (wm << 13);
    const int shBn = nb + 16384 + ((wn >> 1) << 13);

    // P1: stage A1(u+1); read aB (used P2/P4); MFMA Q00 = aA x bR(=bA)
    if (u < NT - 1) STG(pA1a, pA1b, nb + 8192);
#pragma unroll
    for (int m = 0; m < 4; ++m) {
      int ix = shA + aBase + (m + 4) * 1024;
      aB[m][0] = *(const bf16x8*)&sh[ix]; aB[m][1] = *(const bf16x8*)&sh[ix ^ 32];
    }
    BAR();
    __builtin_amdgcn_s_setprio(1);
    MM4x2(0, 0, aA, bR);
    __builtin_amdgcn_s_setprio(0);
    BAR();

    // P2: stage B1(u+1); MFMA Q10 = aB x bR(=bA); refill bR <- bB;
    //     counted wait (drains A0/B0 of tile u+1)
    if (u < NT - 1) STG(pB1a, pB1b, nb + 24576);
    BAR();
    __builtin_amdgcn_s_setprio(1);
    MM4x2(4, 0, aB, bR);
    __builtin_amdgcn_s_setprio(0);
#pragma unroll
    for (int n = 0; n < 2; ++n) {
      int ix = shB + bBase + (n + 2) * 1024;
      bR[n][0] = *(const bf16x8*)&sh[ix]; bR[n][1] = *(const bf16x8*)&sh[ix ^ 32];
    }
    WAITV4();
    BAR();

    // P3: stage A0(u+2); MFMA Q01 = aA x bR(=bB); refill aA <- next tile A0
    if (u < NT - 2) STG(pA0a, pA0b, cb + 0);
    BAR();
    __builtin_amdgcn_s_setprio(1);
    MM4x2(0, 2, aA, bR);
    __builtin_amdgcn_s_setprio(0);
    if (u < NT - 1) {
#pragma unroll
      for (int m = 0; m < 4; ++m) {
        int ix = shAn + aBase + m * 1024;
        aA[m][0] = *(const bf16x8*)&sh[ix]; aA[m][1] = *(const bf16x8*)&sh[ix ^ 32];
      }
    }
    BAR();

    // P4: stage B0(u+2); counted wait (drains A1/B1 of u+1);
    //     MFMA Q11 = aB x bR(=bB); refill bR <- next tile bA
    if (u < NT - 2) { STG(pB0a, pB0b, cb + 16384); WAITV4(); }
    else            { WAITV0(); }
    BAR();
    __builtin_amdgcn_s_setprio(1);
    MM4x2(4, 2, aB, bR);
    __builtin_amdgcn_s_setprio(0);
    if (u < NT - 1) {
#pragma unroll
      for (int n = 0; n < 2; ++n) {
        int ix = shBn + bBase + n * 1024;
        bR[n][0] = *(const bf16x8*)&sh[ix]; bR[n][1] = *(const bf16x8*)&sh[ix ^ 32];
      }
    }
    BAR();
  }
#undef STG
#undef MM4x2

  // epilogue
  const int crow0 = tm * 256 + wm * 128 + g * 4;
  const int ccol0 = tn * 256 + wn * 64 + l15;
#pragma unroll
  for (int mf = 0; mf < 8; ++mf)
#pragma unroll
    for (int n = 0; n < 4; ++n)
#pragma unroll
      for (int q = 0; q < 4; ++q)
        C[(size_t)(crow0 + mf * 16 + q) * D_OUT + ccol0 + n * 16] = acc[mf][n][q];
}

// ---------------------------------------------------------------------------
extern "C" void kernel_launch(void* const* d_in, const int* in_sizes, int n_in,
                              void* d_out, int out_size, void* d_ws, size_t ws_size,
                              hipStream_t stream) {
  const float* x      = (const float*)d_in[0];
  const float* base_w = (const float*)d_in[1];
  const float* gate_w = (const float*)d_in[2];
  const float* lora_A = (const float*)d_in[3];
  const float* lora_B = (const float*)d_in[4];
  float* out = (float*)d_out;

  char* ws = (char*)d_ws;
  u16* xb       = (u16*)ws;                                     // 75,497,472 B
  u16* wb       = (u16*)(ws + 75497472);                        // 37,748,736 B
  u16* la       = (u16*)(ws + 75497472 + 37748736);             //  4,194,304 B
  float* wdense = (float*)(ws + 75497472 + 37748736 + 4194304); //  1,048,576 B

  hipLaunchKernelGGL(k_gate,      dim3(NTOK / TT),    dim3(256), 0, stream,
                     x, gate_w, wdense, xb);
  hipLaunchKernelGGL(k_wconv,     dim3(D_OUT + RMOE), dim3(256), 0, stream,
                     base_w, lora_B, lora_A, wb, la);
  hipLaunchKernelGGL(k_gemm_ax,   dim3((NTOK/64) * (RMOE/128)),  dim3(256), 0, stream,
                     xb, la, wdense, xb);
  hipLaunchKernelGGL(k_gemm_main, dim3((NTOK/256) * (D_OUT/256)), dim3(512), 0, stream,
                     xb, wb, out);
}

// Round 11
// 377.902 us; speedup vs baseline: 1.3322x; 1.0328x over previous
//
#include <hip/hip_runtime.h>

// MoE-LoRA linear, MI355X (gfx950).
// out = x @ base_w^T + 2.0 * ((x @ lora_A^T) * topk_gate_w) @ lora_B^T
// A_cat[8192][4608] = [ bf16(x) | bf16(SCALING * w_e * (x . lora_A_row)) ]
// W_cat[4096][4608] = [ bf16(base_w) | bf16(lora_B) ]
// Main GEMM: R7-proven 256x256-tile 8-wave 4-phase counted-vmcnt schedule
// (264 us, MfmaUtil 52%; R5 32x32-MFMA, R8 unroll, R9 barrier-merge all
// regressed -- frozen). Gate kernel: T14 register-prefetch double-buffer
// (issue chunk kt+1 global loads before computing chunk kt from LDS).

#define D_IN   4096
#define D_OUT  4096
#define NTOK   8192      // B*S
#define NE     32
#define RMOE   512       // E*R
#define KCAT   4608      // D_IN + RMOE
#define SCALING 2.0f

typedef unsigned short u16;
typedef __attribute__((ext_vector_type(4)))  float  f32x4;
typedef __attribute__((ext_vector_type(4)))  unsigned short u16x4;
typedef __attribute__((ext_vector_type(8)))  short  bf16x8;

__device__ __forceinline__ u16 f2bf(float f) {
  unsigned u = __float_as_uint(f);
  u += 0x7FFFu + ((u >> 16) & 1u);        // round-to-nearest-even
  return (u16)(u >> 16);
}

__device__ __forceinline__ void gload16(const void* g, void* l) {
  __builtin_amdgcn_global_load_lds(
      (const __attribute__((address_space(1))) unsigned*)g,
      (__attribute__((address_space(3))) unsigned*)l, 16, 0, 0);
}

#define BAR() do { asm volatile("" ::: "memory"); \
                   __builtin_amdgcn_s_barrier();  \
                   asm volatile("" ::: "memory"); } while (0)
#define WAITV6() asm volatile("s_waitcnt vmcnt(6)" ::: "memory")
#define WAITV4() asm volatile("s_waitcnt vmcnt(4)" ::: "memory")
#define WAITV0() asm volatile("s_waitcnt vmcnt(0)" ::: "memory")

// ---------------------------------------------------------------------------
// Kernel 1: gating logits GEMM + top-2 + renorm -> wdense, fused with
//           x -> bf16 into A_cat[:, 0:4096].  256 blocks.
// T14 pipeline per kt-chunk: regs hold chunk kt; {sync; regs->LDS(+xb);
// sync; issue kt+1 loads; compute kt from LDS} -- HBM latency hides under
// the ~2k-cycle FMA phase (was fully serial stage->compute).
// ---------------------------------------------------------------------------
#define TT 32
#define KC 256

__global__ __launch_bounds__(256) void k_gate(
    const float* __restrict__ x, const float* __restrict__ gate_w,
    float* __restrict__ wdense, u16* __restrict__ xb)
{
  __shared__ float smem[2 * TT * KC];       // xs | gs  (64 KiB)
  __shared__ float lgt[TT * 36];
  __shared__ int   e1s[TT]; __shared__ int   e2s[TT];
  __shared__ float w1s[TT]; __shared__ float w2s[TT];
  const int tid = threadIdx.x;

  float* xs = smem;
  float* gs = smem + TT * KC;
  const int lane = tid & 63, wave = tid >> 6;
  const int ks = lane >> 4, tg = (lane >> 2) & 3, eg = lane & 3;
  const int row0 = blockIdx.x * TT;
  const int kc0 = wave * 16 + ks * 4;

  float acc[8][8];
#pragma unroll
  for (int t = 0; t < 8; ++t)
#pragma unroll
    for (int e = 0; e < 8; ++e) acc[t][e] = 0.f;

  // register prefetch buffers: chunk kt of x-tile and gate-tile
  f32x4 vx[8], vg[8];
#pragma unroll
  for (int i = 0; i < 8; ++i) {             // prologue: load chunk 0
    int c = tid + i * 256;
    int tok = c >> 6, kq = c & 63;
    vx[i] = ((const f32x4*)(x + (size_t)(row0 + tok) * D_IN))[kq];
    vg[i] = ((const f32x4*)(gate_w + (size_t)tok * D_IN))[kq];
  }

  for (int kt = 0; kt < D_IN / KC; ++kt) {
    __syncthreads();                        // prior compute done reading LDS
#pragma unroll
    for (int i = 0; i < 8; ++i) {           // regs -> LDS (+ xb bf16 copy)
      int c = tid + i * 256;
      int tok = c >> 6, kq = c & 63;
      *(f32x4*)&xs[tok * KC + ((kq ^ (tok >> 3)) << 2)] = vx[i];
      u16x4 h;
      h[0] = f2bf(vx[i][0]); h[1] = f2bf(vx[i][1]);
      h[2] = f2bf(vx[i][2]); h[3] = f2bf(vx[i][3]);
      ((u16x4*)(xb + (size_t)(row0 + tok) * KCAT + kt * KC))[kq] = h;
      *(f32x4*)&gs[tok * KC + ((kq ^ (tok >> 3)) << 2)] = vg[i];
    }
    __syncthreads();
    if (kt < D_IN / KC - 1) {               // issue next chunk's loads now;
#pragma unroll
      for (int i = 0; i < 8; ++i) {         // they land under the compute
        int c = tid + i * 256;
        int tok = c >> 6, kq = c & 63;
        vx[i] = ((const f32x4*)(x + (size_t)(row0 + tok) * D_IN + (kt + 1) * KC))[kq];
        vg[i] = ((const f32x4*)(gate_w + (size_t)tok * D_IN + (kt + 1) * KC))[kq];
      }
    }
#pragma unroll
    for (int j = 0; j < 4; ++j) {           // compute chunk kt from LDS
      const int Kc = kc0 + j;
      f32x4 xv[8], gv[8];
#pragma unroll
      for (int t = 0; t < 8; ++t)
        xv[t] = *(const f32x4*)&xs[(tg * 8 + t) * KC + ((Kc ^ tg) << 2)];
#pragma unroll
      for (int e = 0; e < 8; ++e)
        gv[e] = *(const f32x4*)&gs[(eg * 8 + e) * KC + ((Kc ^ eg) << 2)];
#pragma unroll
      for (int t = 0; t < 8; ++t)
#pragma unroll
        for (int e = 0; e < 8; ++e)
#pragma unroll
          for (int m = 0; m < 4; ++m)
            acc[t][e] += xv[t][m] * gv[e][m];
    }
  }

#pragma unroll
  for (int t = 0; t < 8; ++t)
#pragma unroll
    for (int e = 0; e < 8; ++e) {
      float v = acc[t][e];
      v += __shfl_xor(v, 16);
      v += __shfl_xor(v, 32);
      acc[t][e] = v;
    }
  __syncthreads();
  float* red = smem;
  if (ks == 0) {
#pragma unroll
    for (int t = 0; t < 8; ++t)
#pragma unroll
      for (int e4 = 0; e4 < 8; e4 += 4) {
        f32x4 v = { acc[t][e4], acc[t][e4 + 1], acc[t][e4 + 2], acc[t][e4 + 3] };
        *(f32x4*)&red[(wave * 16 + tg * 4 + eg) * 64 + t * 8 + e4] = v;
      }
  }
  __syncthreads();
  {
    int tok = tid >> 3, e4 = (tid & 7) << 2;
    f32x4 s = {0.f, 0.f, 0.f, 0.f};
#pragma unroll
    for (int w = 0; w < 4; ++w)
      s += *(const f32x4*)&red[(w * 16 + (tok >> 3) * 4 + (e4 >> 3)) * 64 + (tok & 7) * 8 + (e4 & 7)];
    *(f32x4*)&lgt[tok * 36 + e4] = s;
  }
  __syncthreads();
  if (tid < TT) {
    float l1 = -1e30f; int e1 = 0;
    for (int e = 0; e < NE; ++e) { float v = lgt[tid * 36 + e]; if (v > l1) { l1 = v; e1 = e; } }
    float l2 = -1e30f; int e2 = 0;
    for (int e = 0; e < NE; ++e) { if (e == e1) continue; float v = lgt[tid * 36 + e]; if (v > l2) { l2 = v; e2 = e; } }
    float t = __expf(l2 - l1);
    float w2 = t / (1.f + t);
    e1s[tid] = e1; e2s[tid] = e2; w1s[tid] = 1.f - w2; w2s[tid] = w2;
  }
  __syncthreads();
#pragma unroll
  for (int i = 0; i < 4; ++i) {
    int c = tid + i * 256;
    int tok = c >> 5, e = c & 31;
    float v = (e == e1s[tok]) ? w1s[tok] : (e == e2s[tok]) ? w2s[tok] : 0.f;
    wdense[(size_t)(row0 + tok) * NE + e] = v;
  }
}

// ---------------------------------------------------------------------------
// Kernel 2: weight conversion to bf16 (wb = [base_w|lora_B], la = lora_A).
// LDS-free pure streaming, full occupancy.
// ---------------------------------------------------------------------------
__global__ __launch_bounds__(256) void k_wconv(
    const float* __restrict__ base_w, const float* __restrict__ lora_B,
    const float* __restrict__ lora_A, u16* __restrict__ wb, u16* __restrict__ la)
{
  const int bid = blockIdx.x, tid = threadIdx.x;
  if (bid < D_OUT) {
    const float* src = base_w + (size_t)bid * D_IN;
    u16* dst = wb + (size_t)bid * KCAT;
#pragma unroll
    for (int i = 0; i < 4; ++i) {
      int c = tid + i * 256;
      f32x4 v = ((const f32x4*)src)[c];
      u16x4 h; h[0] = f2bf(v[0]); h[1] = f2bf(v[1]); h[2] = f2bf(v[2]); h[3] = f2bf(v[3]);
      ((u16x4*)dst)[c] = h;
    }
    if (tid < 128) {                        // lora_B row: 512 = 128 x float4
      f32x4 v = ((const f32x4*)(lora_B + (size_t)bid * RMOE))[tid];
      u16x4 h; h[0] = f2bf(v[0]); h[1] = f2bf(v[1]); h[2] = f2bf(v[2]); h[3] = f2bf(v[3]);
      ((u16x4*)(dst + D_IN))[tid] = h;
    }
  } else {
    int r = bid - D_OUT;                    // lora_A row 0..511
    const float* src = lora_A + (size_t)r * D_IN;
    u16* dst = la + (size_t)r * D_IN;
#pragma unroll
    for (int i = 0; i < 4; ++i) {
      int c = tid + i * 256;
      f32x4 v = ((const f32x4*)src)[c];
      u16x4 h; h[0] = f2bf(v[0]); h[1] = f2bf(v[1]); h[2] = f2bf(v[2]); h[3] = f2bf(v[3]);
      ((u16x4*)dst)[c] = h;
    }
  }
}

// ---------------------------------------------------------------------------
// Kernel 3: ax GEMM  (A_cat[:, :4096] @ lora_A^T) * w * SCALING -> A_cat tail
// 64x128 tile, 512 blocks, BK=64, 4 waves (1Mx4N), 3-buffer pipeline 2 ahead,
// vmcnt(6), XOR swizzle.  (R6-proven, frozen)
// ---------------------------------------------------------------------------
__global__ __launch_bounds__(256) void k_gemm_ax(
    const u16* __restrict__ A, const u16* __restrict__ La,
    const float* __restrict__ wdense, u16* __restrict__ xb)
{
  __shared__ u16 sh[36864];                 // 3 bufs x (As 4096 | Bs 8192)
  const int nwg = gridDim.x;                // 512 (div by 8 -> bijective)
  int bid = blockIdx.x;
  int wg = (bid & 7) * (nwg >> 3) + (bid >> 3);
  const int tm = wg >> 2, tn = wg & 3;      // 128 m-tiles, 4 n-tiles
  const int tid = threadIdx.x;
  const int lane = tid & 63, wn = tid >> 6; // 4 waves split N
  const int l15 = lane & 15, g = lane >> 4;
  const int row0 = tm * 64, col0 = tn * 128;

  size_t offA[2], offB[4]; int dA[2], dB[4];
#pragma unroll
  for (int i = 0; i < 2; ++i) {
    int c = tid + i * 256;
    int r = c >> 3, s = (c & 7) ^ (r & 7);
    offA[i] = (size_t)(row0 + r) * KCAT + s * 8;
    dA[i] = c * 8;
  }
#pragma unroll
  for (int i = 0; i < 4; ++i) {
    int c = tid + i * 256;
    int r = c >> 3, s = (c & 7) ^ (r & 7);
    offB[i] = (size_t)(col0 + r) * D_IN + s * 8;
    dB[i] = c * 8;
  }

#define STGAX(b, kt) do { \
    _Pragma("unroll") for (int i = 0; i < 2; ++i) \
      gload16(A  + offA[i] + (size_t)(kt) * 64, &sh[(b) * 12288 + dA[i]]); \
    _Pragma("unroll") for (int i = 0; i < 4; ++i) \
      gload16(La + offB[i] + (size_t)(kt) * 64, &sh[(b) * 12288 + 4096 + dB[i]]); } while (0)

  f32x4 acc[4][2];
#pragma unroll
  for (int i = 0; i < 4; ++i)
#pragma unroll
    for (int j = 0; j < 2; ++j) acc[i][j] = (f32x4){0.f, 0.f, 0.f, 0.f};

  STGAX(0, 0);
  STGAX(1, 1);
  WAITV6();                                 // tile0 landed
  BAR();

  const int swz = (g ^ (l15 & 7)) * 8;
  for (int kt = 0; kt < D_IN / 64; ++kt) {  // 64 tiles
    if (kt + 2 < D_IN / 64) STGAX((kt + 2) % 3, kt + 2);
    const u16* As_ = &sh[(kt % 3) * 12288];
    const u16* Bs_ = &sh[(kt % 3) * 12288 + 4096];
    bf16x8 af[4][2], bfr[2][2];
#pragma unroll
    for (int i = 0; i < 4; ++i) {
      int ixa = (i * 16 + l15) * 64 + swz;
      af[i][0] = *(const bf16x8*)&As_[ixa]; af[i][1] = *(const bf16x8*)&As_[ixa ^ 32];
    }
#pragma unroll
    for (int j = 0; j < 2; ++j) {
      int ixb = (wn * 32 + j * 16 + l15) * 64 + swz;
      bfr[j][0] = *(const bf16x8*)&Bs_[ixb]; bfr[j][1] = *(const bf16x8*)&Bs_[ixb ^ 32];
    }
    __builtin_amdgcn_s_setprio(1);
#pragma unroll
    for (int i = 0; i < 4; ++i)
#pragma unroll
      for (int j = 0; j < 2; ++j)
#pragma unroll
        for (int kk = 0; kk < 2; ++kk)
          acc[i][j] = __builtin_amdgcn_mfma_f32_16x16x32_bf16(af[i][kk], bfr[j][kk], acc[i][j], 0, 0, 0);
    __builtin_amdgcn_s_setprio(0);
    if (kt >= D_IN / 64 - 2) WAITV0(); else WAITV6();
    BAR();
  }
#undef STGAX

  // epilogue: scale by gate weight, SCALING, store bf16 to A_cat tail
#pragma unroll
  for (int i = 0; i < 4; ++i) {
    int rbase = row0 + i * 16 + (g << 2);
#pragma unroll
    for (int j = 0; j < 2; ++j) {
      int cb = col0 + wn * 32 + j * 16 + l15;
#pragma unroll
      for (int q = 0; q < 4; ++q) {
        int trow = rbase + q;
        float wgt = wdense[(size_t)trow * NE + (cb >> 4)];
        xb[(size_t)trow * KCAT + D_IN + cb] = f2bf(acc[i][j][q] * wgt * SCALING);
      }
    }
  }
}

// ---------------------------------------------------------------------------
// Kernel 4: main GEMM  out = A_cat @ W_cat^T  (M=8192, N=4096, K=4608)
// R7-proven: 256x256 tile, 8 waves (2Mx4N), 16x16x32 bf16 MFMA, BK=64,
// dbuf 128 KiB LDS, 4 phases/K-tile, counted vmcnt(4) x2, XOR-swizzled LDS,
// one-phase-ahead fragment reads.  (frozen)
// ---------------------------------------------------------------------------
#define NT (KCAT / 64)    // 72

__global__ __launch_bounds__(512, 2) void k_gemm_main(
    const u16* __restrict__ A, const u16* __restrict__ Bw, float* __restrict__ C)
{
  // [buf:2][op A|B:2][half:2][128 rows][64 cols] u16 = 128 KiB
  __shared__ u16 sh[65536];

  const int tid  = threadIdx.x;
  const int lane = tid & 63;
  const int wv   = tid >> 6;            // 0..7
  const int wm   = wv >> 2;             // 0..1
  const int wn   = wv & 3;              // 0..3
  const int l15  = lane & 15, g = lane >> 4;

  // T1: bijective XCD swizzle (512 blocks, 512 % 8 == 0)
  const int nwg = gridDim.x;
  int bid = blockIdx.x;
  int wg = (bid & 7) * (nwg >> 3) + (bid >> 3);
  const int tn = wg & 15, tm = wg >> 4; // 16 n-tiles, 32 m-tiles

  // LDS read addressing (T2 swizzle: slot ^= row&7; row&7 == l15&7)
  const int rsw   = (g ^ (l15 & 7)) * 8;
  const int aBase = l15 * 64 + rsw;
  const int bBase = ((wn & 1) * 64 + l15) * 64 + rsw;

  // staging: pre-swizzled global sources, linear gload_lds dests
  const int c0 = tid, c1 = tid + 512;
  const int r0s = c0 >> 3, s0s = (c0 & 7) ^ (r0s & 7);
  const int r1s = c1 >> 3, s1s = (c1 & 7) ^ (r1s & 7);
  const size_t offc0 = (size_t)r0s * KCAT + s0s * 8;
  const size_t offc1 = (size_t)r1s * KCAT + s1s * 8;
  const u16* pA0a = A  + (size_t)(tm * 256 +   0) * KCAT + offc0;
  const u16* pA0b = A  + (size_t)(tm * 256 +   0) * KCAT + offc1;
  const u16* pA1a = A  + (size_t)(tm * 256 + 128) * KCAT + offc0;
  const u16* pA1b = A  + (size_t)(tm * 256 + 128) * KCAT + offc1;
  const u16* pB0a = Bw + (size_t)(tn * 256 +   0) * KCAT + offc0;
  const u16* pB0b = Bw + (size_t)(tn * 256 +   0) * KCAT + offc1;
  const u16* pB1a = Bw + (size_t)(tn * 256 + 128) * KCAT + offc0;
  const u16* pB1b = Bw + (size_t)(tn * 256 + 128) * KCAT + offc1;
  const int d0 = c0 * 8, d1 = c1 * 8;

#define STG(pa, pb, base) do { \
    gload16((pa), &sh[(base) + d0]); \
    gload16((pb), &sh[(base) + d1]); \
    (pa) += 64; (pb) += 64; } while (0)

#define MM4x2(MO, NO, AF, BF) do { \
    _Pragma("unroll") for (int m_ = 0; m_ < 4; ++m_) \
    _Pragma("unroll") for (int n_ = 0; n_ < 2; ++n_) \
    _Pragma("unroll") for (int kk_ = 0; kk_ < 2; ++kk_) \
      acc[m_ + (MO)][n_ + (NO)] = __builtin_amdgcn_mfma_f32_16x16x32_bf16( \
          AF[m_][kk_], BF[n_][kk_], acc[m_ + (MO)][n_ + (NO)], 0, 0, 0); } while (0)

  f32x4 acc[8][4];
#pragma unroll
  for (int i = 0; i < 8; ++i)
#pragma unroll
    for (int j = 0; j < 4; ++j) acc[i][j] = (f32x4){0.f, 0.f, 0.f, 0.f};

  // prologue: tile0 (4 halves) + tile1 (A0,B0); then read tile0 aA,bA
  STG(pA0a, pA0b,     0);
  STG(pB0a, pB0b, 16384);
  STG(pA1a, pA1b,  8192);
  STG(pB1a, pB1b, 24576);
  STG(pA0a, pA0b, 32768 +     0);
  STG(pB0a, pB0b, 32768 + 16384);
  WAITV4();
  BAR();

  bf16x8 aA[4][2], aB[4][2], bR[2][2];
  {
    const int shA = (wm << 13);
    const int shB = 16384 + ((wn >> 1) << 13);
#pragma unroll
    for (int m = 0; m < 4; ++m) {
      int ix = shA + aBase + m * 1024;
      aA[m][0] = *(const bf16x8*)&sh[ix]; aA[m][1] = *(const bf16x8*)&sh[ix ^ 32];
    }
#pragma unroll
    for (int n = 0; n < 2; ++n) {
      int ix = shB + bBase + n * 1024;
      bR[n][0] = *(const bf16x8*)&sh[ix]; bR[n][1] = *(const bf16x8*)&sh[ix ^ 32];
    }
  }

  for (int u = 0; u < NT; ++u) {
    const int cb = (u & 1) << 15;
    const int nb = cb ^ 32768;
    const int shA  = cb + (wm << 13);
    const int shB  = cb + 16384 + ((wn >> 1) << 13);
    const int shAn = nb + (wm << 13);
    const int shBn = nb + 16384 + ((wn >> 1) << 13);

    // P1: stage A1(u+1); read aB (used P2/P4); MFMA Q00 = aA x bR(=bA)
    if (u < NT - 1) STG(pA1a, pA1b, nb + 8192);
#pragma unroll
    for (int m = 0; m < 4; ++m) {
      int ix = shA + aBase + (m + 4) * 1024;
      aB[m][0] = *(const bf16x8*)&sh[ix]; aB[m][1] = *(const bf16x8*)&sh[ix ^ 32];
    }
    BAR();
    __builtin_amdgcn_s_setprio(1);
    MM4x2(0, 0, aA, bR);
    __builtin_amdgcn_s_setprio(0);
    BAR();

    // P2: stage B1(u+1); MFMA Q10 = aB x bR(=bA); refill bR <- bB;
    //     counted wait (drains A0/B0 of tile u+1)
    if (u < NT - 1) STG(pB1a, pB1b, nb + 24576);
    BAR();
    __builtin_amdgcn_s_setprio(1);
    MM4x2(4, 0, aB, bR);
    __builtin_amdgcn_s_setprio(0);
#pragma unroll
    for (int n = 0; n < 2; ++n) {
      int ix = shB + bBase + (n + 2) * 1024;
      bR[n][0] = *(const bf16x8*)&sh[ix]; bR[n][1] = *(const bf16x8*)&sh[ix ^ 32];
    }
    WAITV4();
    BAR();

    // P3: stage A0(u+2); MFMA Q01 = aA x bR(=bB); refill aA <- next tile A0
    if (u < NT - 2) STG(pA0a, pA0b, cb + 0);
    BAR();
    __builtin_amdgcn_s_setprio(1);
    MM4x2(0, 2, aA, bR);
    __builtin_amdgcn_s_setprio(0);
    if (u < NT - 1) {
#pragma unroll
      for (int m = 0; m < 4; ++m) {
        int ix = shAn + aBase + m * 1024;
        aA[m][0] = *(const bf16x8*)&sh[ix]; aA[m][1] = *(const bf16x8*)&sh[ix ^ 32];
      }
    }
    BAR();

    // P4: stage B0(u+2); counted wait (drains A1/B1 of u+1);
    //     MFMA Q11 = aB x bR(=bB); refill bR <- next tile bA
    if (u < NT - 2) { STG(pB0a, pB0b, cb + 16384); WAITV4(); }
    else            { WAITV0(); }
    BAR();
    __builtin_amdgcn_s_setprio(1);
    MM4x2(4, 2, aB, bR);
    __builtin_amdgcn_s_setprio(0);
    if (u < NT - 1) {
#pragma unroll
      for (int n = 0; n < 2; ++n) {
        int ix = shBn + bBase + n * 1024;
        bR[n][0] = *(const bf16x8*)&sh[ix]; bR[n][1] = *(const bf16x8*)&sh[ix ^ 32];
      }
    }
    BAR();
  }
#undef STG
#undef MM4x2

  // epilogue
  const int crow0 = tm * 256 + wm * 128 + g * 4;
  const int ccol0 = tn * 256 + wn * 64 + l15;
#pragma unroll
  for (int mf = 0; mf < 8; ++mf)
#pragma unroll
    for (int n = 0; n < 4; ++n)
#pragma unroll
      for (int q = 0; q < 4; ++q)
        C[(size_t)(crow0 + mf * 16 + q) * D_OUT + ccol0 + n * 16] = acc[mf][n][q];
}

// ---------------------------------------------------------------------------
extern "C" void kernel_launch(void* const* d_in, const int* in_sizes, int n_in,
                              void* d_out, int out_size, void* d_ws, size_t ws_size,
                              hipStream_t stream) {
  const float* x      = (const float*)d_in[0];
  const float* base_w = (const float*)d_in[1];
  const float* gate_w = (const float*)d_in[2];
  const float* lora_A = (const float*)d_in[3];
  const float* lora_B = (const float*)d_in[4];
  float* out = (float*)d_out;

  char* ws = (char*)d_ws;
  u16* xb       = (u16*)ws;                                     // 75,497,472 B
  u16* wb       = (u16*)(ws + 75497472);                        // 37,748,736 B
  u16* la       = (u16*)(ws + 75497472 + 37748736);             //  4,194,304 B
  float* wdense = (float*)(ws + 75497472 + 37748736 + 4194304); //  1,048,576 B

  hipLaunchKernelGGL(k_gate,      dim3(NTOK / TT),    dim3(256), 0, stream,
                     x, gate_w, wdense, xb);
  hipLaunchKernelGGL(k_wconv,     dim3(D_OUT + RMOE), dim3(256), 0, stream,
                     base_w, lora_B, lora_A, wb, la);
  hipLaunchKernelGGL(k_gemm_ax,   dim3((NTOK/64) * (RMOE/128)),  dim3(256), 0, stream,
                     xb, la, wdense, xb);
  hipLaunchKernelGGL(k_gemm_main, dim3((NTOK/256) * (D_OUT/256)), dim3(512), 0, stream,
                     xb, wb, out);
}

// Round 13
// 372.626 us; speedup vs baseline: 1.3511x; 1.0142x over previous
//
#include <hip/hip_runtime.h>

// MoE-LoRA linear, MI355X (gfx950).
// out = x @ base_w^T + 2.0 * ((x @ lora_A^T) * topk_gate_w) @ lora_B^T
// A_cat[8192][4608] = [ bf16(x) | bf16(SCALING * w_e * (x . lora_A_row)) ]
// W_cat[4096][4608] = [ bf16(base_w) | bf16(lora_B) ]
// Main GEMM: R7-proven 256x256-tile 8-wave 4-phase counted-vmcnt schedule
// (264 us, MfmaUtil 52%; R5 32x32-MFMA, R8 unroll, R9 barrier-merge all
// regressed -- frozen). Gate kernel: T14 register-prefetch double-buffer.
// R12's kernel-merge (la rider + wconv-in-ax) FAILED correctness (absmax
// 0.855, cause not statically identifiable) -- REVERTED to R11-proven
// 4-launch structure. Do not re-merge without a debuggable harness.

#define D_IN   4096
#define D_OUT  4096
#define NTOK   8192      // B*S
#define NE     32
#define RMOE   512       // E*R
#define KCAT   4608      // D_IN + RMOE
#define SCALING 2.0f

typedef unsigned short u16;
typedef __attribute__((ext_vector_type(4)))  float  f32x4;
typedef __attribute__((ext_vector_type(4)))  unsigned short u16x4;
typedef __attribute__((ext_vector_type(8)))  short  bf16x8;

__device__ __forceinline__ u16 f2bf(float f) {
  unsigned u = __float_as_uint(f);
  u += 0x7FFFu + ((u >> 16) & 1u);        // round-to-nearest-even
  return (u16)(u >> 16);
}

__device__ __forceinline__ void gload16(const void* g, void* l) {
  __builtin_amdgcn_global_load_lds(
      (const __attribute__((address_space(1))) unsigned*)g,
      (__attribute__((address_space(3))) unsigned*)l, 16, 0, 0);
}

#define BAR() do { asm volatile("" ::: "memory"); \
                   __builtin_amdgcn_s_barrier();  \
                   asm volatile("" ::: "memory"); } while (0)
#define WAITV6() asm volatile("s_waitcnt vmcnt(6)" ::: "memory")
#define WAITV4() asm volatile("s_waitcnt vmcnt(4)" ::: "memory")
#define WAITV0() asm volatile("s_waitcnt vmcnt(0)" ::: "memory")

// ---------------------------------------------------------------------------
// Kernel 1: gating logits GEMM + top-2 + renorm -> wdense, fused with
//           x -> bf16 into A_cat[:, 0:4096].  256 blocks.
// T14 pipeline per kt-chunk: regs hold chunk kt; {sync; regs->LDS(+xb);
// sync; issue kt+1 loads; compute kt from LDS}.
// ---------------------------------------------------------------------------
#define TT 32
#define KC 256

__global__ __launch_bounds__(256) void k_gate(
    const float* __restrict__ x, const float* __restrict__ gate_w,
    float* __restrict__ wdense, u16* __restrict__ xb)
{
  __shared__ float smem[2 * TT * KC];       // xs | gs  (64 KiB)
  __shared__ float lgt[TT * 36];
  __shared__ int   e1s[TT]; __shared__ int   e2s[TT];
  __shared__ float w1s[TT]; __shared__ float w2s[TT];
  const int tid = threadIdx.x;

  float* xs = smem;
  float* gs = smem + TT * KC;
  const int lane = tid & 63, wave = tid >> 6;
  const int ks = lane >> 4, tg = (lane >> 2) & 3, eg = lane & 3;
  const int row0 = blockIdx.x * TT;
  const int kc0 = wave * 16 + ks * 4;

  float acc[8][8];
#pragma unroll
  for (int t = 0; t < 8; ++t)
#pragma unroll
    for (int e = 0; e < 8; ++e) acc[t][e] = 0.f;

  // register prefetch buffers: chunk kt of x-tile and gate-tile
  f32x4 vx[8], vg[8];
#pragma unroll
  for (int i = 0; i < 8; ++i) {             // prologue: load chunk 0
    int c = tid + i * 256;
    int tok = c >> 6, kq = c & 63;
    vx[i] = ((const f32x4*)(x + (size_t)(row0 + tok) * D_IN))[kq];
    vg[i] = ((const f32x4*)(gate_w + (size_t)tok * D_IN))[kq];
  }

  for (int kt = 0; kt < D_IN / KC; ++kt) {
    __syncthreads();                        // prior compute done reading LDS
#pragma unroll
    for (int i = 0; i < 8; ++i) {           // regs -> LDS (+ xb bf16 copy)
      int c = tid + i * 256;
      int tok = c >> 6, kq = c & 63;
      *(f32x4*)&xs[tok * KC + ((kq ^ (tok >> 3)) << 2)] = vx[i];
      u16x4 h;
      h[0] = f2bf(vx[i][0]); h[1] = f2bf(vx[i][1]);
      h[2] = f2bf(vx[i][2]); h[3] = f2bf(vx[i][3]);
      ((u16x4*)(xb + (size_t)(row0 + tok) * KCAT + kt * KC))[kq] = h;
      *(f32x4*)&gs[tok * KC + ((kq ^ (tok >> 3)) << 2)] = vg[i];
    }
    __syncthreads();
    if (kt < D_IN / KC - 1) {               // issue next chunk's loads now;
#pragma unroll
      for (int i = 0; i < 8; ++i) {         // they land under the compute
        int c = tid + i * 256;
        int tok = c >> 6, kq = c & 63;
        vx[i] = ((const f32x4*)(x + (size_t)(row0 + tok) * D_IN + (kt + 1) * KC))[kq];
        vg[i] = ((const f32x4*)(gate_w + (size_t)tok * D_IN + (kt + 1) * KC))[kq];
      }
    }
#pragma unroll
    for (int j = 0; j < 4; ++j) {           // compute chunk kt from LDS
      const int Kc = kc0 + j;
      f32x4 xv[8], gv[8];
#pragma unroll
      for (int t = 0; t < 8; ++t)
        xv[t] = *(const f32x4*)&xs[(tg * 8 + t) * KC + ((Kc ^ tg) << 2)];
#pragma unroll
      for (int e = 0; e < 8; ++e)
        gv[e] = *(const f32x4*)&gs[(eg * 8 + e) * KC + ((Kc ^ eg) << 2)];
#pragma unroll
      for (int t = 0; t < 8; ++t)
#pragma unroll
        for (int e = 0; e < 8; ++e)
#pragma unroll
          for (int m = 0; m < 4; ++m)
            acc[t][e] += xv[t][m] * gv[e][m];
    }
  }

#pragma unroll
  for (int t = 0; t < 8; ++t)
#pragma unroll
    for (int e = 0; e < 8; ++e) {
      float v = acc[t][e];
      v += __shfl_xor(v, 16);
      v += __shfl_xor(v, 32);
      acc[t][e] = v;
    }
  __syncthreads();
  float* red = smem;
  if (ks == 0) {
#pragma unroll
    for (int t = 0; t < 8; ++t)
#pragma unroll
      for (int e4 = 0; e4 < 8; e4 += 4) {
        f32x4 v = { acc[t][e4], acc[t][e4 + 1], acc[t][e4 + 2], acc[t][e4 + 3] };
        *(f32x4*)&red[(wave * 16 + tg * 4 + eg) * 64 + t * 8 + e4] = v;
      }
  }
  __syncthreads();
  {
    int tok = tid >> 3, e4 = (tid & 7) << 2;
    f32x4 s = {0.f, 0.f, 0.f, 0.f};
#pragma unroll
    for (int w = 0; w < 4; ++w)
      s += *(const f32x4*)&red[(w * 16 + (tok >> 3) * 4 + (e4 >> 3)) * 64 + (tok & 7) * 8 + (e4 & 7)];
    *(f32x4*)&lgt[tok * 36 + e4] = s;
  }
  __syncthreads();
  if (tid < TT) {
    float l1 = -1e30f; int e1 = 0;
    for (int e = 0; e < NE; ++e) { float v = lgt[tid * 36 + e]; if (v > l1) { l1 = v; e1 = e; } }
    float l2 = -1e30f; int e2 = 0;
    for (int e = 0; e < NE; ++e) { if (e == e1) continue; float v = lgt[tid * 36 + e]; if (v > l2) { l2 = v; e2 = e; } }
    float t = __expf(l2 - l1);
    float w2 = t / (1.f + t);
    e1s[tid] = e1; e2s[tid] = e2; w1s[tid] = 1.f - w2; w2s[tid] = w2;
  }
  __syncthreads();
#pragma unroll
  for (int i = 0; i < 4; ++i) {
    int c = tid + i * 256;
    int tok = c >> 5, e = c & 31;
    float v = (e == e1s[tok]) ? w1s[tok] : (e == e2s[tok]) ? w2s[tok] : 0.f;
    wdense[(size_t)(row0 + tok) * NE + e] = v;
  }
}

// ---------------------------------------------------------------------------
// Kernel 2: weight conversion to bf16 (wb = [base_w|lora_B], la = lora_A).
// LDS-free pure streaming, full occupancy.
// ---------------------------------------------------------------------------
__global__ __launch_bounds__(256) void k_wconv(
    const float* __restrict__ base_w, const float* __restrict__ lora_B,
    const float* __restrict__ lora_A, u16* __restrict__ wb, u16* __restrict__ la)
{
  const int bid = blockIdx.x, tid = threadIdx.x;
  if (bid < D_OUT) {
    const float* src = base_w + (size_t)bid * D_IN;
    u16* dst = wb + (size_t)bid * KCAT;
#pragma unroll
    for (int i = 0; i < 4; ++i) {
      int c = tid + i * 256;
      f32x4 v = ((const f32x4*)src)[c];
      u16x4 h; h[0] = f2bf(v[0]); h[1] = f2bf(v[1]); h[2] = f2bf(v[2]); h[3] = f2bf(v[3]);
      ((u16x4*)dst)[c] = h;
    }
    if (tid < 128) {                        // lora_B row: 512 = 128 x float4
      f32x4 v = ((const f32x4*)(lora_B + (size_t)bid * RMOE))[tid];
      u16x4 h; h[0] = f2bf(v[0]); h[1] = f2bf(v[1]); h[2] = f2bf(v[2]); h[3] = f2bf(v[3]);
      ((u16x4*)(dst + D_IN))[tid] = h;
    }
  } else {
    int r = bid - D_OUT;                    // lora_A row 0..511
    const float* src = lora_A + (size_t)r * D_IN;
    u16* dst = la + (size_t)r * D_IN;
#pragma unroll
    for (int i = 0; i < 4; ++i) {
      int c = tid + i * 256;
      f32x4 v = ((const f32x4*)src)[c];
      u16x4 h; h[0] = f2bf(v[0]); h[1] = f2bf(v[1]); h[2] = f2bf(v[2]); h[3] = f2bf(v[3]);
      ((u16x4*)dst)[c] = h;
    }
  }
}

// ---------------------------------------------------------------------------
// Kernel 3: ax GEMM  (A_cat[:, :4096] @ lora_A^T) * w * SCALING -> A_cat tail
// 64x128 tile, 512 blocks, BK=64, 4 waves (1Mx4N), 3-buffer pipeline 2 ahead,
// vmcnt(6), XOR swizzle.  (R6-proven, frozen)
// ---------------------------------------------------------------------------
__global__ __launch_bounds__(256) void k_gemm_ax(
    const u16* __restrict__ A, const u16* __restrict__ La,
    const float* __restrict__ wdense, u16* __restrict__ xb)
{
  __shared__ u16 sh[36864];                 // 3 bufs x (As 4096 | Bs 8192)
  const int nwg = gridDim.x;                // 512 (div by 8 -> bijective)
  int bid = blockIdx.x;
  int wg = (bid & 7) * (nwg >> 3) + (bid >> 3);
  const int tm = wg >> 2, tn = wg & 3;      // 128 m-tiles, 4 n-tiles
  const int tid = threadIdx.x;
  const int lane = tid & 63, wn = tid >> 6; // 4 waves split N
  const int l15 = lane & 15, g = lane >> 4;
  const int row0 = tm * 64, col0 = tn * 128;

  size_t offA[2], offB[4]; int dA[2], dB[4];
#pragma unroll
  for (int i = 0; i < 2; ++i) {
    int c = tid + i * 256;
    int r = c >> 3, s = (c & 7) ^ (r & 7);
    offA[i] = (size_t)(row0 + r) * KCAT + s * 8;
    dA[i] = c * 8;
  }
#pragma unroll
  for (int i = 0; i < 4; ++i) {
    int c = tid + i * 256;
    int r = c >> 3, s = (c & 7) ^ (r & 7);
    offB[i] = (size_t)(col0 + r) * D_IN + s * 8;
    dB[i] = c * 8;
  }

#define STGAX(b, kt) do { \
    _Pragma("unroll") for (int i = 0; i < 2; ++i) \
      gload16(A  + offA[i] + (size_t)(kt) * 64, &sh[(b) * 12288 + dA[i]]); \
    _Pragma("unroll") for (int i = 0; i < 4; ++i) \
      gload16(La + offB[i] + (size_t)(kt) * 64, &sh[(b) * 12288 + 4096 + dB[i]]); } while (0)

  f32x4 acc[4][2];
#pragma unroll
  for (int i = 0; i < 4; ++i)
#pragma unroll
    for (int j = 0; j < 2; ++j) acc[i][j] = (f32x4){0.f, 0.f, 0.f, 0.f};

  STGAX(0, 0);
  STGAX(1, 1);
  WAITV6();                                 // tile0 landed
  BAR();

  const int swz = (g ^ (l15 & 7)) * 8;
  for (int kt = 0; kt < D_IN / 64; ++kt) {  // 64 tiles
    if (kt + 2 < D_IN / 64) STGAX((kt + 2) % 3, kt + 2);
    const u16* As_ = &sh[(kt % 3) * 12288];
    const u16* Bs_ = &sh[(kt % 3) * 12288 + 4096];
    bf16x8 af[4][2], bfr[2][2];
#pragma unroll
    for (int i = 0; i < 4; ++i) {
      int ixa = (i * 16 + l15) * 64 + swz;
      af[i][0] = *(const bf16x8*)&As_[ixa]; af[i][1] = *(const bf16x8*)&As_[ixa ^ 32];
    }
#pragma unroll
    for (int j = 0; j < 2; ++j) {
      int ixb = (wn * 32 + j * 16 + l15) * 64 + swz;
      bfr[j][0] = *(const bf16x8*)&Bs_[ixb]; bfr[j][1] = *(const bf16x8*)&Bs_[ixb ^ 32];
    }
    __builtin_amdgcn_s_setprio(1);
#pragma unroll
    for (int i = 0; i < 4; ++i)
#pragma unroll
      for (int j = 0; j < 2; ++j)
#pragma unroll
        for (int kk = 0; kk < 2; ++kk)
          acc[i][j] = __builtin_amdgcn_mfma_f32_16x16x32_bf16(af[i][kk], bfr[j][kk], acc[i][j], 0, 0, 0);
    __builtin_amdgcn_s_setprio(0);
    if (kt >= D_IN / 64 - 2) WAITV0(); else WAITV6();
    BAR();
  }
#undef STGAX

  // epilogue: scale by gate weight, SCALING, store bf16 to A_cat tail
#pragma unroll
  for (int i = 0; i < 4; ++i) {
    int rbase = row0 + i * 16 + (g << 2);
#pragma unroll
    for (int j = 0; j < 2; ++j) {
      int cb = col0 + wn * 32 + j * 16 + l15;
#pragma unroll
      for (int q = 0; q < 4; ++q) {
        int trow = rbase + q;
        float wgt = wdense[(size_t)trow * NE + (cb >> 4)];
        xb[(size_t)trow * KCAT + D_IN + cb] = f2bf(acc[i][j][q] * wgt * SCALING);
      }
    }
  }
}

// ---------------------------------------------------------------------------
// Kernel 4: main GEMM  out = A_cat @ W_cat^T  (M=8192, N=4096, K=4608)
// R7-proven: 256x256 tile, 8 waves (2Mx4N), 16x16x32 bf16 MFMA, BK=64,
// dbuf 128 KiB LDS, 4 phases/K-tile, counted vmcnt(4) x2, XOR-swizzled LDS,
// one-phase-ahead fragment reads.  (frozen)
// ---------------------------------------------------------------------------
#define NT (KCAT / 64)    // 72

__global__ __launch_bounds__(512, 2) void k_gemm_main(
    const u16* __restrict__ A, const u16* __restrict__ Bw, float* __restrict__ C)
{
  // [buf:2][op A|B:2][half:2][128 rows][64 cols] u16 = 128 KiB
  __shared__ u16 sh[65536];

  const int tid  = threadIdx.x;
  const int lane = tid & 63;
  const int wv   = tid >> 6;            // 0..7
  const int wm   = wv >> 2;             // 0..1
  const int wn   = wv & 3;              // 0..3
  const int l15  = lane & 15, g = lane >> 4;

  // T1: bijective XCD swizzle (512 blocks, 512 % 8 == 0)
  const int nwg = gridDim.x;
  int bid = blockIdx.x;
  int wg = (bid & 7) * (nwg >> 3) + (bid >> 3);
  const int tn = wg & 15, tm = wg >> 4; // 16 n-tiles, 32 m-tiles

  // LDS read addressing (T2 swizzle: slot ^= row&7; row&7 == l15&7)
  const int rsw   = (g ^ (l15 & 7)) * 8;
  const int aBase = l15 * 64 + rsw;
  const int bBase = ((wn & 1) * 64 + l15) * 64 + rsw;

  // staging: pre-swizzled global sources, linear gload_lds dests
  const int c0 = tid, c1 = tid + 512;
  const int r0s = c0 >> 3, s0s = (c0 & 7) ^ (r0s & 7);
  const int r1s = c1 >> 3, s1s = (c1 & 7) ^ (r1s & 7);
  const size_t offc0 = (size_t)r0s * KCAT + s0s * 8;
  const size_t offc1 = (size_t)r1s * KCAT + s1s * 8;
  const u16* pA0a = A  + (size_t)(tm * 256 +   0) * KCAT + offc0;
  const u16* pA0b = A  + (size_t)(tm * 256 +   0) * KCAT + offc1;
  const u16* pA1a = A  + (size_t)(tm * 256 + 128) * KCAT + offc0;
  const u16* pA1b = A  + (size_t)(tm * 256 + 128) * KCAT + offc1;
  const u16* pB0a = Bw + (size_t)(tn * 256 +   0) * KCAT + offc0;
  const u16* pB0b = Bw + (size_t)(tn * 256 +   0) * KCAT + offc1;
  const u16* pB1a = Bw + (size_t)(tn * 256 + 128) * KCAT + offc0;
  const u16* pB1b = Bw + (size_t)(tn * 256 + 128) * KCAT + offc1;
  const int d0 = c0 * 8, d1 = c1 * 8;

#define STG(pa, pb, base) do { \
    gload16((pa), &sh[(base) + d0]); \
    gload16((pb), &sh[(base) + d1]); \
    (pa) += 64; (pb) += 64; } while (0)

#define MM4x2(MO, NO, AF, BF) do { \
    _Pragma("unroll") for (int m_ = 0; m_ < 4; ++m_) \
    _Pragma("unroll") for (int n_ = 0; n_ < 2; ++n_) \
    _Pragma("unroll") for (int kk_ = 0; kk_ < 2; ++kk_) \
      acc[m_ + (MO)][n_ + (NO)] = __builtin_amdgcn_mfma_f32_16x16x32_bf16( \
          AF[m_][kk_], BF[n_][kk_], acc[m_ + (MO)][n_ + (NO)], 0, 0, 0); } while (0)

  f32x4 acc[8][4];
#pragma unroll
  for (int i = 0; i < 8; ++i)
#pragma unroll
    for (int j = 0; j < 4; ++j) acc[i][j] = (f32x4){0.f, 0.f, 0.f, 0.f};

  // prologue: tile0 (4 halves) + tile1 (A0,B0); then read tile0 aA,bA
  STG(pA0a, pA0b,     0);
  STG(pB0a, pB0b, 16384);
  STG(pA1a, pA1b,  8192);
  STG(pB1a, pB1b, 24576);
  STG(pA0a, pA0b, 32768 +     0);
  STG(pB0a, pB0b, 32768 + 16384);
  WAITV4();
  BAR();

  bf16x8 aA[4][2], aB[4][2], bR[2][2];
  {
    const int shA = (wm << 13);
    const int shB = 16384 + ((wn >> 1) << 13);
#pragma unroll
    for (int m = 0; m < 4; ++m) {
      int ix = shA + aBase + m * 1024;
      aA[m][0] = *(const bf16x8*)&sh[ix]; aA[m][1] = *(const bf16x8*)&sh[ix ^ 32];
    }
#pragma unroll
    for (int n = 0; n < 2; ++n) {
      int ix = shB + bBase + n * 1024;
      bR[n][0] = *(const bf16x8*)&sh[ix]; bR[n][1] = *(const bf16x8*)&sh[ix ^ 32];
    }
  }

  for (int u = 0; u < NT; ++u) {
    const int cb = (u & 1) << 15;
    const int nb = cb ^ 32768;
    const int shA  = cb + (wm << 13);
    const int shB  = cb + 16384 + ((wn >> 1) << 13);
    const int shAn = nb + (wm << 13);
    const int shBn = nb + 16384 + ((wn >> 1) << 13);

    // P1: stage A1(u+1); read aB (used P2/P4); MFMA Q00 = aA x bR(=bA)
    if (u < NT - 1) STG(pA1a, pA1b, nb + 8192);
#pragma unroll
    for (int m = 0; m < 4; ++m) {
      int ix = shA + aBase + (m + 4) * 1024;
      aB[m][0] = *(const bf16x8*)&sh[ix]; aB[m][1] = *(const bf16x8*)&sh[ix ^ 32];
    }
    BAR();
    __builtin_amdgcn_s_setprio(1);
    MM4x2(0, 0, aA, bR);
    __builtin_amdgcn_s_setprio(0);
    BAR();

    // P2: stage B1(u+1); MFMA Q10 = aB x bR(=bA); refill bR <- bB;
    //     counted wait (drains A0/B0 of tile u+1)
    if (u < NT - 1) STG(pB1a, pB1b, nb + 24576);
    BAR();
    __builtin_amdgcn_s_setprio(1);
    MM4x2(4, 0, aB, bR);
    __builtin_amdgcn_s_setprio(0);
#pragma unroll
    for (int n = 0; n < 2; ++n) {
      int ix = shB + bBase + (n + 2) * 1024;
      bR[n][0] = *(const bf16x8*)&sh[ix]; bR[n][1] = *(const bf16x8*)&sh[ix ^ 32];
    }
    WAITV4();
    BAR();

    // P3: stage A0(u+2); MFMA Q01 = aA x bR(=bB); refill aA <- next tile A0
    if (u < NT - 2) STG(pA0a, pA0b, cb + 0);
    BAR();
    __builtin_amdgcn_s_setprio(1);
    MM4x2(0, 2, aA, bR);
    __builtin_amdgcn_s_setprio(0);
    if (u < NT - 1) {
#pragma unroll
      for (int m = 0; m < 4; ++m) {
        int ix = shAn + aBase + m * 1024;
        aA[m][0] = *(const bf16x8*)&sh[ix]; aA[m][1] = *(const bf16x8*)&sh[ix ^ 32];
      }
    }
    BAR();

    // P4: stage B0(u+2); counted wait (drains A1/B1 of u+1);
    //     MFMA Q11 = aB x bR(=bB); refill bR <- next tile bA
    if (u < NT - 2) { STG(pB0a, pB0b, cb + 16384); WAITV4(); }
    else            { WAITV0(); }
    BAR();
    __builtin_amdgcn_s_setprio(1);
    MM4x2(4, 2, aB, bR);
    __builtin_amdgcn_s_setprio(0);
    if (u < NT - 1) {
#pragma unroll
      for (int n = 0; n < 2; ++n) {
        int ix = shBn + bBase + n * 1024;
        bR[n][0] = *(const bf16x8*)&sh[ix]; bR[n][1] = *(const bf16x8*)&sh[ix ^ 32];
      }
    }
    BAR();
  }
#undef STG
#undef MM4x2

  // epilogue
  const int crow0 = tm * 256 + wm * 128 + g * 4;
  const int ccol0 = tn * 256 + wn * 64 + l15;
#pragma unroll
  for (int mf = 0; mf < 8; ++mf)
#pragma unroll
    for (int n = 0; n < 4; ++n)
#pragma unroll
      for (int q = 0; q < 4; ++q)
        C[(size_t)(crow0 + mf * 16 + q) * D_OUT + ccol0 + n * 16] = acc[mf][n][q];
}

// ---------------------------------------------------------------------------
extern "C" void kernel_launch(void* const* d_in, const int* in_sizes, int n_in,
                              void* d_out, int out_size, void* d_ws, size_t ws_size,
                              hipStream_t stream) {
  const float* x      = (const float*)d_in[0];
  const float* base_w = (const float*)d_in[1];
  const float* gate_w = (const float*)d_in[2];
  const float* lora_A = (const float*)d_in[3];
  const float* lora_B = (const float*)d_in[4];
  float* out = (float*)d_out;

  char* ws = (char*)d_ws;
  u16* xb       = (u16*)ws;                                     // 75,497,472 B
  u16* wb       = (u16*)(ws + 75497472);                        // 37,748,736 B
  u16* la       = (u16*)(ws + 75497472 + 37748736);             //  4,194,304 B
  float* wdense = (float*)(ws + 75497472 + 37748736 + 4194304); //  1,048,576 B

  hipLaunchKernelGGL(k_gate,      dim3(NTOK / TT),    dim3(256), 0, stream,
                     x, gate_w, wdense, xb);
  hipLaunchKernelGGL(k_wconv,     dim3(D_OUT + RMOE), dim3(256), 0, stream,
                     base_w, lora_B, lora_A, wb, la);
  hipLaunchKernelGGL(k_gemm_ax,   dim3((NTOK/64) * (RMOE/128)),  dim3(256), 0, stream,
                     xb, la, wdense, xb);
  hipLaunchKernelGGL(k_gemm_main, dim3((NTOK/256) * (D_OUT/256)), dim3(512), 0, stream,
                     xb, wb, out);
}